// Round 1
// baseline (1715.483 us; speedup 1.0000x reference)
//
#include <hip/hip_runtime.h>
#include <math.h>

#define BB 16
#define NN 4096
#define SS 8
#define DD 64
#define DHH 128
#define CIN 66
#define NITERS 3
#define LN_EPS_F 1e-5f
#define EPS_ATTN_F 1e-8f
#define QSCALE 0.125f    // d^-0.5

__device__ __forceinline__ float dot4(float4 a, float4 b) {
    return fmaf(a.x, b.x, fmaf(a.y, b.y, fmaf(a.z, b.z, a.w * b.w)));
}

// ---------------------------------------------------------------- init slots
__global__ __launch_bounds__(256) void k_init_slots(
    const float* __restrict__ slots_in, float* __restrict__ slots,
    float* __restrict__ positions, float* __restrict__ scales) {
    int tid = blockIdx.x * 256 + threadIdx.x;
    if (tid < BB * SS * DD) {
        int s = (tid / DD) % SS;
        int c = tid % DD;
        slots[tid] = slots_in[s * 68 + c];
    }
    if (tid < BB * SS * 2) {
        int s = (tid >> 1) & 7;
        int p = tid & 1;
        float po = slots_in[s * 68 + 64 + p];
        positions[tid] = fminf(fmaxf(po, -1.f), 1.f);
        float sc = slots_in[s * 68 + 66 + p];
        scales[tid] = fminf(fmaxf(sc, 1e-3f), 2.f);
    }
}

// ---------------------------------------------------------------- k,v = feats @ Wk.T / Wv.T
__global__ __launch_bounds__(256) void k_compute_kv(
    const float* __restrict__ inp, const float* __restrict__ Wk,
    const float* __restrict__ Wv, float* __restrict__ kbuf, float* __restrict__ vbuf) {
    __shared__ float xt[32 * 68];
    int blk = blockIdx.x;          // 2048 blocks
    int b = blk >> 7;
    int n0 = (blk & 127) << 5;
    int tid = threadIdx.x;
    {
        int r = tid >> 3, c0 = (tid & 7) * 8;
        const float* src = inp + ((size_t)(b * NN + n0 + r)) * CIN + c0;
        float* dst = &xt[r * 68 + c0];
        #pragma unroll
        for (int q = 0; q < 4; q++) {
            float2 a = *(const float2*)(src + 2 * q);
            dst[2 * q] = a.x; dst[2 * q + 1] = a.y;
        }
    }
    __syncthreads();
    int r = tid >> 3, j = tid & 7;
    float acck[8], accv[8];
    #pragma unroll
    for (int i = 0; i < 8; i++) { acck[i] = 0.f; accv[i] = 0.f; }
    for (int c4 = 0; c4 < 64; c4 += 4) {
        float4 x4 = *(const float4*)&xt[r * 68 + c4];
        #pragma unroll
        for (int ii = 0; ii < 8; ii++) {
            int i = j * 8 + ii;
            acck[ii] += dot4(x4, *(const float4*)(Wk + i * 64 + c4));
            accv[ii] += dot4(x4, *(const float4*)(Wv + i * 64 + c4));
        }
    }
    size_t base = ((size_t)(b * NN + n0 + r)) * DD + j * 8;
    #pragma unroll
    for (int ii = 0; ii < 8; ii++) { kbuf[base + ii] = acck[ii]; vbuf[base + ii] = accv[ii]; }
}

// ---------------------------------------------------------------- slot_prep: w2q, qb2
__global__ __launch_bounds__(512) void k_slot_prep(
    const float* __restrict__ slots, const float* __restrict__ lsg,
    const float* __restrict__ lsb, const float* __restrict__ Wq,
    const float* __restrict__ W2, const float* __restrict__ b2,
    float* __restrict__ w2q, float* __restrict__ qb2) {
    __shared__ float sn[512];
    __shared__ float qv[SS][64];
    __shared__ float wsum[8], wsum2[8];
    int b = blockIdx.x, t = threadIdx.x;
    int s = t >> 6, c = t & 63;
    float x = slots[(b * SS + s) * DD + c];
    float sum = x;
    for (int off = 32; off; off >>= 1) sum += __shfl_xor(sum, off, 64);
    float m = sum * (1.f / 64.f);
    float dv = x - m;
    float vs = dv * dv;
    for (int off = 32; off; off >>= 1) vs += __shfl_xor(vs, off, 64);
    float y = dv * rsqrtf(vs * (1.f / 64.f) + LN_EPS_F) * lsg[c] + lsb[c];
    float s1 = y, s2 = y * y;
    for (int off = 32; off; off >>= 1) { s1 += __shfl_xor(s1, off, 64); s2 += __shfl_xor(s2, off, 64); }
    if (c == 0) { wsum[s] = s1; wsum2[s] = s2; }
    __syncthreads();
    float ts1 = 0.f, ts2 = 0.f;
    #pragma unroll
    for (int i = 0; i < 8; i++) { ts1 += wsum[i]; ts2 += wsum2[i]; }
    float gm = ts1 * (1.f / 512.f);
    float gv = ts2 * (1.f / 512.f) - gm * gm;
    sn[t] = (y - gm) * rsqrtf(gv + LN_EPS_F);
    __syncthreads();
    float acc = 0.f;
    for (int j4 = 0; j4 < 64; j4 += 4)
        acc += dot4(*(const float4*)&sn[s * 64 + j4], *(const float4*)(Wq + c * 64 + j4));
    qv[s][c] = acc;
    __syncthreads();
    float a0 = 0.f, a1 = 0.f;
    for (int cc = 0; cc < 64; cc++) {
        float qc = qv[s][cc];
        a0 = fmaf(qc, W2[cc * DHH + c], a0);
        a1 = fmaf(qc, W2[cc * DHH + c + 64], a1);
    }
    w2q[(b * SS + s) * DHH + c] = a0 * QSCALE;
    w2q[(b * SS + s) * DHH + c + 64] = a1 * QSCALE;
    float qb = qv[s][c] * b2[c];
    for (int off = 32; off; off >>= 1) qb += __shfl_xor(qb, off, 64);
    if (c == 0) qb2[b * SS + s] = qb * QSCALE;
}

// ---------------------------------------------------------------- shared helpers
__device__ __forceinline__ void stage_w1(const float* __restrict__ W1, float* w1s) {
    int tid = threadIdx.x;
    int o = tid >> 1, h = tid & 1;
    const float4* src = (const float4*)(W1 + o * 64 + h * 32);
    float4* dst = (float4*)(w1s + o * 68 + h * 32);
    #pragma unroll
    for (int q = 0; q < 8; q++) dst[q] = src[q];
}

// phase A: xn[r][*] = LN(base_row + rgp) * g + b   (64 rows, stride 68)
__device__ __forceinline__ void stage_xn(
    const float* __restrict__ base, const float* __restrict__ inp,
    int b, int s, int n0,
    const float* __restrict__ positions, const float* __restrict__ scales,
    const float* __restrict__ Wg, const float* __restrict__ bg,
    const float* __restrict__ lpg, const float* __restrict__ lpb,
    float* xn) {
    int tid = threadIdx.x;
    int bs = b * SS + s;
    float p0 = positions[bs * 2 + 0], p1 = positions[bs * 2 + 1];
    float c0 = scales[bs * 2 + 0], c1 = scales[bs * 2 + 1];
    int r = tid >> 2, sub = tid & 3;
    size_t rowi = (size_t)(b * NN + n0 + r);
    float g0 = inp[rowi * CIN + 64];
    float g1 = inp[rowi * CIN + 65];
    float rel0 = (g0 - p0) / c0;
    float rel1 = (g1 - p1) / c1;
    const float* krow = base + rowi * DD + sub * 16;
    float xv[16];
    float sum = 0.f;
    #pragma unroll
    for (int q = 0; q < 4; q++) {
        float4 k4 = ((const float4*)krow)[q];
        int cb = sub * 16 + q * 4;
        float v0 = k4.x + rel0 * Wg[(cb + 0) * 2] + rel1 * Wg[(cb + 0) * 2 + 1] + bg[cb + 0];
        float v1 = k4.y + rel0 * Wg[(cb + 1) * 2] + rel1 * Wg[(cb + 1) * 2 + 1] + bg[cb + 1];
        float v2 = k4.z + rel0 * Wg[(cb + 2) * 2] + rel1 * Wg[(cb + 2) * 2 + 1] + bg[cb + 2];
        float v3 = k4.w + rel0 * Wg[(cb + 3) * 2] + rel1 * Wg[(cb + 3) * 2 + 1] + bg[cb + 3];
        xv[q * 4 + 0] = v0; xv[q * 4 + 1] = v1; xv[q * 4 + 2] = v2; xv[q * 4 + 3] = v3;
        sum += v0 + v1 + v2 + v3;
    }
    sum += __shfl_xor(sum, 1, 64);
    sum += __shfl_xor(sum, 2, 64);
    float m = sum * (1.f / 64.f);
    float vs = 0.f;
    #pragma unroll
    for (int q = 0; q < 16; q++) { float d = xv[q] - m; vs += d * d; }
    vs += __shfl_xor(vs, 1, 64);
    vs += __shfl_xor(vs, 2, 64);
    float rstd = rsqrtf(vs * (1.f / 64.f) + LN_EPS_F);
    #pragma unroll
    for (int q = 0; q < 16; q++) {
        int cc = sub * 16 + q;
        xn[r * 68 + cc] = (xv[q] - m) * rstd * lpg[cc] + lpb[cc];
    }
}

// matmul1: 2 rows x 16 outs per thread; rp=tid>>3, og=tid&7, o = og + 8*t
__device__ __forceinline__ void mm1(const float* xn, const float* w1s,
                                    int rp, int og, float* acc0, float* acc1) {
    const float* xr0 = xn + (rp * 2) * 68;
    const float* xr1 = xr0 + 68;
    for (int i4 = 0; i4 < 64; i4 += 4) {
        float4 xa = *(const float4*)(xr0 + i4);
        float4 xb = *(const float4*)(xr1 + i4);
        #pragma unroll
        for (int t = 0; t < 16; t++) {
            float4 w = *(const float4*)(w1s + (og + t * 8) * 68 + i4);
            acc0[t] = fmaf(xa.x, w.x, fmaf(xa.y, w.y, fmaf(xa.z, w.z, fmaf(xa.w, w.w, acc0[t]))));
            acc1[t] = fmaf(xb.x, w.x, fmaf(xb.y, w.y, fmaf(xb.z, w.z, fmaf(xb.w, w.w, acc1[t]))));
        }
    }
}

// ---------------------------------------------------------------- pass1: dots
__global__ __launch_bounds__(256) void k_pass1(
    const float* __restrict__ kbuf, const float* __restrict__ inp,
    const float* __restrict__ positions, const float* __restrict__ scales,
    const float* __restrict__ Wg, const float* __restrict__ bg,
    const float* __restrict__ lpg, const float* __restrict__ lpb,
    const float* __restrict__ W1, const float* __restrict__ b1,
    const float* __restrict__ w2q, const float* __restrict__ qb2,
    float* __restrict__ dots) {
    __shared__ float xn[64 * 68];
    __shared__ float w1s[128 * 68];
    __shared__ float w2ql[128];
    __shared__ float b1l[128];
    int n0 = blockIdx.x << 6;
    int s = blockIdx.y, b = blockIdx.z;
    int tid = threadIdx.x;
    int bs = b * SS + s;
    stage_w1(W1, w1s);
    if (tid < 128) { w2ql[tid] = w2q[bs * DHH + tid]; b1l[tid] = b1[tid]; }
    stage_xn(kbuf, inp, b, s, n0, positions, scales, Wg, bg, lpg, lpb, xn);
    __syncthreads();
    int rp = tid >> 3, og = tid & 7;
    float acc0[16], acc1[16];
    #pragma unroll
    for (int t = 0; t < 16; t++) { acc0[t] = 0.f; acc1[t] = 0.f; }
    mm1(xn, w1s, rp, og, acc0, acc1);
    float d0 = 0.f, d1 = 0.f;
    #pragma unroll
    for (int t = 0; t < 16; t++) {
        int o = og + t * 8;
        float h0 = fmaxf(acc0[t] + b1l[o], 0.f);
        float h1 = fmaxf(acc1[t] + b1l[o], 0.f);
        float wq = w2ql[o];
        d0 = fmaf(h0, wq, d0);
        d1 = fmaf(h1, wq, d1);
    }
    d0 += __shfl_xor(d0, 1, 64); d1 += __shfl_xor(d1, 1, 64);
    d0 += __shfl_xor(d0, 2, 64); d1 += __shfl_xor(d1, 2, 64);
    d0 += __shfl_xor(d0, 4, 64); d1 += __shfl_xor(d1, 4, 64);
    if (og == 0) {
        float qb = qb2[bs];
        dots[((size_t)(b * NN + n0 + rp * 2)) * SS + s] = qb + d0;
        dots[((size_t)(b * NN + n0 + rp * 2 + 1)) * SS + s] = qb + d1;
    }
}

// ---------------------------------------------------------------- softmax M,L per (b,s)
__global__ __launch_bounds__(256) void k_softmax_ms(
    const float* __restrict__ dots, float* __restrict__ Mv, float* __restrict__ Lv) {
    __shared__ float red[256];
    int bs = blockIdx.x;
    int b = bs >> 3, s = bs & 7;
    int t = threadIdx.x;
    const float* dp = dots + (size_t)b * NN * SS + s;
    float mx = -1e30f;
    for (int n = t; n < NN; n += 256) mx = fmaxf(mx, dp[(size_t)n * SS]);
    red[t] = mx;
    __syncthreads();
    for (int off = 128; off; off >>= 1) {
        if (t < off) red[t] = fmaxf(red[t], red[t + off]);
        __syncthreads();
    }
    float M = red[0];
    __syncthreads();
    float sm = 0.f;
    for (int n = t; n < NN; n += 256) sm += expf(dp[(size_t)n * SS] - M);
    red[t] = sm;
    __syncthreads();
    for (int off = 128; off; off >>= 1) {
        if (t < off) red[t] += red[t + off];
        __syncthreads();
    }
    if (t == 0) { Mv[bs] = M; Lv[bs] = red[0]; }
}

// ---------------------------------------------------------------- attn normalize
__global__ __launch_bounds__(256) void k_attn_norm(
    const float* __restrict__ dots, const float* __restrict__ Mv,
    const float* __restrict__ Lv, float* __restrict__ attn) {
    __shared__ float Ml[8], Rl[8];
    int b = blockIdx.x >> 4;
    int t = threadIdx.x;
    if (t < 8) { Ml[t] = Mv[b * 8 + t]; Rl[t] = 1.f / Lv[b * 8 + t]; }
    __syncthreads();
    int n = (blockIdx.x & 15) * 256 + t;
    const float* dp = dots + ((size_t)(b * NN + n)) * SS;
    float a[8];
    float rs = 0.f;
    #pragma unroll
    for (int s = 0; s < 8; s++) {
        a[s] = expf(dp[s] - Ml[s]) * Rl[s] + EPS_ATTN_F;
        rs += a[s];
    }
    float inv = 1.f / rs;
    float* ap = attn + ((size_t)(b * NN + n)) * SS;
    #pragma unroll
    for (int s = 0; s < 8; s++) ap[s] = a[s] * inv;
}

// ---------------------------------------------------------------- pass2: H, stats
__global__ __launch_bounds__(256) void k_pass2(
    const float* __restrict__ vbuf, const float* __restrict__ inp,
    const float* __restrict__ positions, const float* __restrict__ scales,
    const float* __restrict__ Wg, const float* __restrict__ bg,
    const float* __restrict__ lpg, const float* __restrict__ lpb,
    const float* __restrict__ W1, const float* __restrict__ b1,
    const float* __restrict__ attn, float* __restrict__ H, float* __restrict__ stats) {
    __shared__ float xn[64 * 68];
    __shared__ float w1s[128 * 68];
    __shared__ float b1l[128];
    __shared__ float attl[64];
    __shared__ float Hw[4 * 128];
    __shared__ float st[5];
    int n0 = blockIdx.x << 6;
    int s = blockIdx.y, b = blockIdx.z;
    int tid = threadIdx.x;
    int bs = b * SS + s;
    stage_w1(W1, w1s);
    if (tid < 128) b1l[tid] = b1[tid];
    if (tid < 5) st[tid] = 0.f;
    __syncthreads();
    stage_xn(vbuf, inp, b, s, n0, positions, scales, Wg, bg, lpg, lpb, xn);
    {
        int r = tid >> 2, sub = tid & 3;
        if (sub == 0) {
            size_t rowi = (size_t)(b * NN + n0 + r);
            float a = attn[rowi * SS + s];
            attl[r] = a;
            float g0 = inp[rowi * CIN + 64];
            float g1 = inp[rowi * CIN + 65];
            atomicAdd(&st[0], a);
            atomicAdd(&st[1], a * g0);
            atomicAdd(&st[2], a * g1);
            atomicAdd(&st[3], a * g0 * g0);
            atomicAdd(&st[4], a * g1 * g1);
        }
    }
    __syncthreads();
    int rp = tid >> 3, og = tid & 7;
    float acc0[16], acc1[16];
    #pragma unroll
    for (int t = 0; t < 16; t++) { acc0[t] = 0.f; acc1[t] = 0.f; }
    mm1(xn, w1s, rp, og, acc0, acc1);
    float aw0 = attl[rp * 2], aw1 = attl[rp * 2 + 1];
    float hp[16];
    #pragma unroll
    for (int t = 0; t < 16; t++) {
        int o = og + t * 8;
        float h0 = fmaxf(acc0[t] + b1l[o], 0.f);
        float h1 = fmaxf(acc1[t] + b1l[o], 0.f);
        hp[t] = fmaf(aw0, h0, aw1 * h1);
    }
    #pragma unroll
    for (int t = 0; t < 16; t++) {
        hp[t] += __shfl_xor(hp[t], 8, 64);
        hp[t] += __shfl_xor(hp[t], 16, 64);
        hp[t] += __shfl_xor(hp[t], 32, 64);
    }
    int wv = tid >> 6;
    if ((tid & 63) < 8) {
        #pragma unroll
        for (int t = 0; t < 16; t++) Hw[wv * 128 + og + t * 8] = hp[t];
    }
    __syncthreads();
    if (tid < 128) {
        float hsum = Hw[tid] + Hw[128 + tid] + Hw[256 + tid] + Hw[384 + tid];
        atomicAdd(&H[bs * DHH + tid], hsum);
    }
    if (tid < 5) atomicAdd(&stats[bs * 5 + tid], st[tid]);
}

// ---------------------------------------------------------------- pass2 final iter: stats only
__global__ __launch_bounds__(256) void k_pass2_final(
    const float* __restrict__ attn, const float* __restrict__ inp,
    float* __restrict__ stats) {
    int bs = blockIdx.x;
    int b = bs >> 3, s = bs & 7;
    int t = threadIdx.x;
    float v0 = 0.f, v1 = 0.f, v2 = 0.f, v3 = 0.f, v4 = 0.f;
    for (int n = t; n < NN; n += 256) {
        size_t rowi = (size_t)(b * NN + n);
        float a = attn[rowi * SS + s];
        float g0 = inp[rowi * CIN + 64];
        float g1 = inp[rowi * CIN + 65];
        v0 += a; v1 += a * g0; v2 += a * g1; v3 += a * g0 * g0; v4 += a * g1 * g1;
    }
    for (int off = 32; off; off >>= 1) {
        v0 += __shfl_xor(v0, off, 64); v1 += __shfl_xor(v1, off, 64);
        v2 += __shfl_xor(v2, off, 64); v3 += __shfl_xor(v3, off, 64);
        v4 += __shfl_xor(v4, off, 64);
    }
    __shared__ float red[4][5];
    if ((t & 63) == 0) {
        int w = t >> 6;
        red[w][0] = v0; red[w][1] = v1; red[w][2] = v2; red[w][3] = v3; red[w][4] = v4;
    }
    __syncthreads();
    if (t < 5) stats[bs * 5 + t] = red[0][t] + red[1][t] + red[2][t] + red[3][t];
}

// ---------------------------------------------------------------- positions/scales
__global__ void k_finalize(const float* __restrict__ stats,
                           float* __restrict__ positions, float* __restrict__ scales) {
    int bs = threadIdx.x;
    if (bs < BB * SS) {
        float A0 = stats[bs * 5 + 0];
        float A1x = stats[bs * 5 + 1], A1y = stats[bs * 5 + 2];
        float A2x = stats[bs * 5 + 3], A2y = stats[bs * 5 + 4];
        positions[bs * 2 + 0] = A1x;
        positions[bs * 2 + 1] = A1y;
        float sx = A2x - A1x * A1x * (2.f - A0);
        float sy = A2y - A1y * A1y * (2.f - A0);
        scales[bs * 2 + 0] = fminf(fmaxf(sqrtf(fmaxf(sx, 0.f)), 1e-3f), 2.f);
        scales[bs * 2 + 1] = fminf(fmaxf(sqrtf(fmaxf(sy, 0.f)), 1e-3f), 2.f);
    }
}

// ---------------------------------------------------------------- GRU + slot MLP
__global__ __launch_bounds__(64) void k_gru_mlp(
    const float* __restrict__ H, const float* __restrict__ stats,
    const float* __restrict__ W2, const float* __restrict__ b2,
    const float* __restrict__ W_ih, const float* __restrict__ W_hh,
    const float* __restrict__ b_ih, const float* __restrict__ b_hh,
    const float* __restrict__ lmg, const float* __restrict__ lmb,
    const float* __restrict__ W3, const float* __restrict__ b3,
    const float* __restrict__ W4, const float* __restrict__ b4,
    float* __restrict__ slots) {
    int bs = blockIdx.x;
    int c = threadIdx.x;
    __shared__ float hl[DHH], ul[DD], sl[DD], yl[DD], hml[DHH];
    hl[c] = H[bs * DHH + c];
    hl[c + 64] = H[bs * DHH + 64 + c];
    float hold = slots[bs * DD + c];
    sl[c] = hold;
    __syncthreads();
    float A0 = stats[bs * 5];
    float u = A0 * b2[c];
    for (int o = 0; o < DHH; o += 4) {
        float4 w = *(const float4*)(W2 + c * DHH + o);
        u = fmaf(w.x, hl[o], fmaf(w.y, hl[o + 1], fmaf(w.z, hl[o + 2], fmaf(w.w, hl[o + 3], u))));
    }
    ul[c] = u;
    __syncthreads();
    float gir = b_ih[c], giz = b_ih[64 + c], gin = b_ih[128 + c];
    float ghr = b_hh[c], ghz = b_hh[64 + c], ghn = b_hh[128 + c];
    for (int k4 = 0; k4 < DD; k4 += 4) {
        float4 uu = *(const float4*)(ul + k4);
        float4 hh = *(const float4*)(sl + k4);
        gir += dot4(uu, *(const float4*)(W_ih + c * DD + k4));
        giz += dot4(uu, *(const float4*)(W_ih + (64 + c) * DD + k4));
        gin += dot4(uu, *(const float4*)(W_ih + (128 + c) * DD + k4));
        ghr += dot4(hh, *(const float4*)(W_hh + c * DD + k4));
        ghz += dot4(hh, *(const float4*)(W_hh + (64 + c) * DD + k4));
        ghn += dot4(hh, *(const float4*)(W_hh + (128 + c) * DD + k4));
    }
    float rg = 1.f / (1.f + expf(-(gir + ghr)));
    float zg = 1.f / (1.f + expf(-(giz + ghz)));
    float ng = tanhf(gin + rg * ghn);
    float snew = (1.f - zg) * ng + zg * hold;
    float sum = snew;
    for (int off = 32; off; off >>= 1) sum += __shfl_xor(sum, off, 64);
    float m = sum * (1.f / 64.f);
    float dv = snew - m;
    float vv = dv * dv;
    for (int off = 32; off; off >>= 1) vv += __shfl_xor(vv, off, 64);
    yl[c] = dv * rsqrtf(vv * (1.f / 64.f) + LN_EPS_F) * lmg[c] + lmb[c];
    __syncthreads();
    float h0 = b3[c], h1 = b3[64 + c];
    for (int k4 = 0; k4 < DD; k4 += 4) {
        float4 yy = *(const float4*)(yl + k4);
        h0 += dot4(yy, *(const float4*)(W3 + c * DD + k4));
        h1 += dot4(yy, *(const float4*)(W3 + (64 + c) * DD + k4));
    }
    hml[c] = fmaxf(h0, 0.f);
    hml[64 + c] = fmaxf(h1, 0.f);
    __syncthreads();
    float outv = b4[c];
    for (int o4 = 0; o4 < DHH; o4 += 4) {
        float4 hm4 = *(const float4*)(hml + o4);
        outv += dot4(hm4, *(const float4*)(W4 + c * DHH + o4));
    }
    slots[bs * DD + c] = outv;
}

// ---------------------------------------------------------------- write out
__global__ __launch_bounds__(256) void k_write_out(
    const float* __restrict__ slots, const float* __restrict__ positions,
    const float* __restrict__ scales, float* __restrict__ out) {
    int tid = blockIdx.x * 256 + threadIdx.x;
    if (tid >= BB * SS * 68) return;
    int bs = tid / 68, c = tid % 68;
    float v;
    if (c < 64) v = slots[bs * 64 + c];
    else if (c < 66) v = positions[bs * 2 + (c - 64)];
    else v = scales[bs * 2 + (c - 66)];
    out[tid] = v;
}

// ---------------------------------------------------------------- launcher
extern "C" void kernel_launch(void* const* d_in, const int* in_sizes, int n_in,
                              void* d_out, int out_size, void* d_ws, size_t ws_size,
                              hipStream_t stream) {
    (void)in_sizes; (void)n_in; (void)out_size; (void)ws_size;
    const float* inp = (const float*)d_in[0];
    const float* slots_in = (const float*)d_in[1];
    const float* Wq = (const float*)d_in[2];
    const float* Wk = (const float*)d_in[3];
    const float* Wv = (const float*)d_in[4];
    const float* Wg = (const float*)d_in[5];
    const float* bg = (const float*)d_in[6];
    const float* lpg = (const float*)d_in[7];
    const float* lpb = (const float*)d_in[8];
    const float* W1 = (const float*)d_in[9];
    const float* b1 = (const float*)d_in[10];
    const float* W2 = (const float*)d_in[11];
    const float* b2 = (const float*)d_in[12];
    const float* W_ih = (const float*)d_in[13];
    const float* W_hh = (const float*)d_in[14];
    const float* b_ih = (const float*)d_in[15];
    const float* b_hh = (const float*)d_in[16];
    const float* lmg = (const float*)d_in[17];
    const float* lmb = (const float*)d_in[18];
    const float* W3 = (const float*)d_in[19];
    const float* b3 = (const float*)d_in[20];
    const float* W4 = (const float*)d_in[21];
    const float* b4 = (const float*)d_in[22];
    const float* lsg = (const float*)d_in[23];
    const float* lsb = (const float*)d_in[24];
    float* out = (float*)d_out;
    float* ws = (float*)d_ws;

    size_t o_k = 0;
    size_t o_v = o_k + (size_t)BB * NN * DD;
    size_t o_dots = o_v + (size_t)BB * NN * DD;
    size_t o_attn = o_dots + (size_t)BB * NN * SS;
    size_t o_slots = o_attn + (size_t)BB * NN * SS;
    size_t o_pos = o_slots + BB * SS * DD;
    size_t o_scl = o_pos + BB * SS * 2;
    size_t o_w2q = o_scl + BB * SS * 2;
    size_t o_qb2 = o_w2q + BB * SS * DHH;
    size_t o_M = o_qb2 + BB * SS;
    size_t o_L = o_M + BB * SS;
    size_t o_H = o_L + BB * SS;
    size_t o_stats = o_H + BB * SS * DHH;

    float* kbuf = ws + o_k;
    float* vbuf = ws + o_v;
    float* dots = ws + o_dots;
    float* attn = ws + o_attn;
    float* slots = ws + o_slots;
    float* positions = ws + o_pos;
    float* scales = ws + o_scl;
    float* w2q = ws + o_w2q;
    float* qb2 = ws + o_qb2;
    float* Mv = ws + o_M;
    float* Lv = ws + o_L;
    float* H = ws + o_H;
    float* stats = ws + o_stats;

    k_init_slots<<<32, 256, 0, stream>>>(slots_in, slots, positions, scales);
    k_compute_kv<<<2048, 256, 0, stream>>>(inp, Wk, Wv, kbuf, vbuf);

    for (int it = 0; it <= NITERS; ++it) {
        k_slot_prep<<<BB, 512, 0, stream>>>(slots, lsg, lsb, Wq, W2, b2, w2q, qb2);
        k_pass1<<<dim3(64, 8, 16), 256, 0, stream>>>(kbuf, inp, positions, scales,
                                                     Wg, bg, lpg, lpb, W1, b1, w2q, qb2, dots);
        k_softmax_ms<<<128, 256, 0, stream>>>(dots, Mv, Lv);
        k_attn_norm<<<256, 256, 0, stream>>>(dots, Mv, Lv, attn);
        if (it < NITERS) {
            hipMemsetAsync(H, 0, (size_t)BB * SS * DHH * sizeof(float), stream);
            hipMemsetAsync(stats, 0, (size_t)BB * SS * 5 * sizeof(float), stream);
            k_pass2<<<dim3(64, 8, 16), 256, 0, stream>>>(vbuf, inp, positions, scales,
                                                         Wg, bg, lpg, lpb, W1, b1, attn, H, stats);
            k_finalize<<<1, 128, 0, stream>>>(stats, positions, scales);
            k_gru_mlp<<<128, 64, 0, stream>>>(H, stats, W2, b2, W_ih, W_hh, b_ih, b_hh,
                                              lmg, lmb, W3, b3, W4, b4, slots);
        } else {
            k_pass2_final<<<128, 256, 0, stream>>>(attn, inp, stats);
            k_finalize<<<1, 128, 0, stream>>>(stats, positions, scales);
        }
    }
    k_write_out<<<34, 256, 0, stream>>>(slots, positions, scales, out);
}

// Round 3
// 846.730 us; speedup vs baseline: 2.0260x; 2.0260x over previous
//
#include <hip/hip_runtime.h>
#include <math.h>

#define BB 16
#define NN 4096
#define SS 8
#define DD 64
#define DHH 128
#define CIN 66
#define NITERS 3
#define LN_EPS_F 1e-5f
#define EPS_ATTN_F 1e-8f
#define QSCALE 0.125f    // d^-0.5
#define RB 8             // blocks along N per (b,s): 8 blocks * 512 rows
#define LO_SCALE 2048.0f
#define LO_INV 4.8828125e-4f   // 1/2048

typedef __attribute__((ext_vector_type(8))) _Float16 half8;
typedef __attribute__((ext_vector_type(4))) float f32x4;

union H8 { half8 v; _Float16 u[8]; };

__device__ __forceinline__ float dot4(float4 a, float4 b) {
    return fmaf(a.x, b.x, fmaf(a.y, b.y, fmaf(a.z, b.z, a.w * b.w)));
}

// scaled fp16 split: z = h + l/2048, h = RTN fp16(z), l = RTN fp16((z-h)*2048).
// reconstruction error ~2^-23 relative.
__device__ __forceinline__ void split_fp16(float z, _Float16& h, _Float16& l) {
    _Float16 hh = (_Float16)z;
    float rem = (z - (float)hh) * LO_SCALE;
    h = hh;
    l = (_Float16)rem;
}

// ---------------------------------------------------------------- init slots
__global__ __launch_bounds__(256) void k_init_slots(
    const float* __restrict__ slots_in, float* __restrict__ slots,
    float* __restrict__ positions, float* __restrict__ scales) {
    int tid = blockIdx.x * 256 + threadIdx.x;
    if (tid < BB * SS * DD) {
        int s = (tid / DD) % SS;
        int c = tid % DD;
        slots[tid] = slots_in[s * 68 + c];
    }
    if (tid < BB * SS * 2) {
        int s = (tid >> 1) & 7;
        int p = tid & 1;
        float po = slots_in[s * 68 + 64 + p];
        positions[tid] = fminf(fmaxf(po, -1.f), 1.f);
        float sc = slots_in[s * 68 + 66 + p];
        scales[tid] = fminf(fmaxf(sc, 1e-3f), 2.f);
    }
}

// ---------------------------------------------------------------- k,v = feats @ Wk.T / Wv.T  (+bg folded in)
__global__ __launch_bounds__(256) void k_compute_kv(
    const float* __restrict__ inp, const float* __restrict__ Wk,
    const float* __restrict__ Wv, const float* __restrict__ bg,
    float* __restrict__ kbuf, float* __restrict__ vbuf) {
    __shared__ float xt[32 * 68];
    int blk = blockIdx.x;          // 2048 blocks
    int b = blk >> 7;
    int n0 = (blk & 127) << 5;
    int tid = threadIdx.x;
    {
        int r = tid >> 3, c0 = (tid & 7) * 8;
        const float* src = inp + ((size_t)(b * NN + n0 + r)) * CIN + c0;
        float* dst = &xt[r * 68 + c0];
        #pragma unroll
        for (int q = 0; q < 4; q++) {
            float2 a = *(const float2*)(src + 2 * q);
            dst[2 * q] = a.x; dst[2 * q + 1] = a.y;
        }
    }
    __syncthreads();
    int r = tid >> 3, j = tid & 7;
    float acck[8], accv[8];
    #pragma unroll
    for (int i = 0; i < 8; i++) { acck[i] = 0.f; accv[i] = 0.f; }
    for (int c4 = 0; c4 < 64; c4 += 4) {
        float4 x4 = *(const float4*)&xt[r * 68 + c4];
        #pragma unroll
        for (int ii = 0; ii < 8; ii++) {
            int i = j * 8 + ii;
            acck[ii] += dot4(x4, *(const float4*)(Wk + i * 64 + c4));
            accv[ii] += dot4(x4, *(const float4*)(Wv + i * 64 + c4));
        }
    }
    size_t base = ((size_t)(b * NN + n0 + r)) * DD + j * 8;
    #pragma unroll
    for (int ii = 0; ii < 8; ii++) {
        float bgi = bg[j * 8 + ii];
        kbuf[base + ii] = acck[ii] + bgi;
        vbuf[base + ii] = accv[ii] + bgi;
    }
}

// ---------------------------------------------------------------- W1 fragment prep
// W1p[o][c] = W1[o][c]*lpg[c]; b1p[o] = b1[o] + sum_c W1[o][c]*lpb[c]
// frag f = ot*2+ks: lane holds W1p[ot*16+(lane&15)][ks*32+(lane>>4)*8+j], fp16 hi/lo(x2048).
__global__ __launch_bounds__(256) void k_w1_frag(
    const float* __restrict__ W1, const float* __restrict__ lpg,
    const float* __restrict__ lpb, const float* __restrict__ b1,
    _Float16* __restrict__ wh, _Float16* __restrict__ wl,
    float* __restrict__ b1p) {
    int idx = blockIdx.x * 256 + threadIdx.x;   // grid 4 -> 1024 = 16 frags * 64 lanes
    int f = idx >> 6, lane = idx & 63;
    int ot = f >> 1, ks = f & 1;
    int o = ot * 16 + (lane & 15);
    int k0 = ks * 32 + (lane >> 4) * 8;
    #pragma unroll
    for (int j = 0; j < 8; j++) {
        float w = W1[o * 64 + k0 + j] * lpg[k0 + j];
        _Float16 h, l;
        split_fp16(w, h, l);
        wh[(size_t)f * 512 + lane * 8 + j] = h;
        wl[(size_t)f * 512 + lane * 8 + j] = l;
    }
    if (blockIdx.x == 0 && threadIdx.x < 128) {
        int oo = threadIdx.x;
        float acc = b1[oo];
        for (int c = 0; c < 64; c++) acc = fmaf(W1[oo * 64 + c], lpb[c], acc);
        b1p[oo] = acc;
    }
}

// ---------------------------------------------------------------- slot_prep: w2q, qb2
__global__ __launch_bounds__(512) void k_slot_prep(
    const float* __restrict__ slots, const float* __restrict__ lsg,
    const float* __restrict__ lsb, const float* __restrict__ Wq,
    const float* __restrict__ W2, const float* __restrict__ b2,
    float* __restrict__ w2q, float* __restrict__ qb2) {
    __shared__ float sn[512];
    __shared__ float qv[SS][64];
    __shared__ float wsum[8], wsum2[8];
    int b = blockIdx.x, t = threadIdx.x;
    int s = t >> 6, c = t & 63;
    float x = slots[(b * SS + s) * DD + c];
    float sum = x;
    for (int off = 32; off; off >>= 1) sum += __shfl_xor(sum, off, 64);
    float m = sum * (1.f / 64.f);
    float dv = x - m;
    float vs = dv * dv;
    for (int off = 32; off; off >>= 1) vs += __shfl_xor(vs, off, 64);
    float y = dv * rsqrtf(vs * (1.f / 64.f) + LN_EPS_F) * lsg[c] + lsb[c];
    float s1 = y, s2 = y * y;
    for (int off = 32; off; off >>= 1) { s1 += __shfl_xor(s1, off, 64); s2 += __shfl_xor(s2, off, 64); }
    if (c == 0) { wsum[s] = s1; wsum2[s] = s2; }
    __syncthreads();
    float ts1 = 0.f, ts2 = 0.f;
    #pragma unroll
    for (int i = 0; i < 8; i++) { ts1 += wsum[i]; ts2 += wsum2[i]; }
    float gm = ts1 * (1.f / 512.f);
    float gv = ts2 * (1.f / 512.f) - gm * gm;
    sn[t] = (y - gm) * rsqrtf(gv + LN_EPS_F);
    __syncthreads();
    float acc = 0.f;
    for (int j4 = 0; j4 < 64; j4 += 4)
        acc += dot4(*(const float4*)&sn[s * 64 + j4], *(const float4*)(Wq + c * 64 + j4));
    qv[s][c] = acc;
    __syncthreads();
    float a0 = 0.f, a1 = 0.f;
    for (int cc = 0; cc < 64; cc++) {
        float qc = qv[s][cc];
        a0 = fmaf(qc, W2[cc * DHH + c], a0);
        a1 = fmaf(qc, W2[cc * DHH + c + 64], a1);
    }
    w2q[(b * SS + s) * DHH + c] = a0 * QSCALE;
    w2q[(b * SS + s) * DHH + c + 64] = a1 * QSCALE;
    float qb = qv[s][c] * b2[c];
    for (int off = 32; off; off >>= 1) qb += __shfl_xor(qb, off, 64);
    if (c == 0) qb2[b * SS + s] = qb * QSCALE;
}

// ---------------------------------------------------------------- MFMA stage helper
// Produces A-fragments for one 16-row tile directly in A-operand layout:
// lane holds row (lane&15), k = (lane>>4)*8+j (+32 for ks=1). fp16 hi + scaled-lo.
__device__ __forceinline__ void stage_afrag(
    const float* __restrict__ base, const float* __restrict__ inp,
    int b, int rowTile, int quad, int col,
    float rel_p0, float rel_p1, float rc0, float rc1,
    const float* __restrict__ wgs,
    half8* ah, half8* al) {
    int rA = rowTile + col;
    size_t rowi = (size_t)(b * NN + rA);
    const float* xr = base + rowi * DD + quad * 8;
    float4 x0 = *(const float4*)(xr);
    float4 x1 = *(const float4*)(xr + 4);
    float4 x2 = *(const float4*)(xr + 32);
    float4 x3 = *(const float4*)(xr + 36);
    float2 g = *(const float2*)(inp + rowi * CIN + 64);
    float rel0 = (g.x - rel_p0) * rc0;
    float rel1 = (g.y - rel_p1) * rc1;
    float y[16];
    {
        float xs[16] = {x0.x, x0.y, x0.z, x0.w, x1.x, x1.y, x1.z, x1.w,
                        x2.x, x2.y, x2.z, x2.w, x3.x, x3.y, x3.z, x3.w};
        #pragma unroll
        for (int jj = 0; jj < 4; jj++) {
            float4 wA = *(const float4*)&wgs[(quad * 8 + 2 * jj) * 2];
            float4 wB = *(const float4*)&wgs[64 + (quad * 8 + 2 * jj) * 2];
            y[2 * jj]     = fmaf(rel0, wA.x, fmaf(rel1, wA.y, xs[2 * jj]));
            y[2 * jj + 1] = fmaf(rel0, wA.z, fmaf(rel1, wA.w, xs[2 * jj + 1]));
            y[8 + 2 * jj]     = fmaf(rel0, wB.x, fmaf(rel1, wB.y, xs[8 + 2 * jj]));
            y[8 + 2 * jj + 1] = fmaf(rel0, wB.z, fmaf(rel1, wB.w, xs[8 + 2 * jj + 1]));
        }
    }
    float sum = 0.f;
    #pragma unroll
    for (int q = 0; q < 16; q++) sum += y[q];
    sum += __shfl_xor(sum, 16, 64);
    sum += __shfl_xor(sum, 32, 64);
    float m = sum * (1.f / 64.f);
    float vs = 0.f;
    #pragma unroll
    for (int q = 0; q < 16; q++) { float d = y[q] - m; vs = fmaf(d, d, vs); }
    vs += __shfl_xor(vs, 16, 64);
    vs += __shfl_xor(vs, 32, 64);
    float rstd = rsqrtf(vs * (1.f / 64.f) + LN_EPS_F);
    H8 h0, h1, l0, l1;
    #pragma unroll
    for (int j = 0; j < 8; j++) {
        float z = (y[j] - m) * rstd;
        split_fp16(z, h0.u[j], l0.u[j]);
        float z2 = (y[8 + j] - m) * rstd;
        split_fp16(z2, h1.u[j], l1.u[j]);
    }
    ah[0] = h0.v; ah[1] = h1.v; al[0] = l0.v; al[1] = l1.v;
}

// ---------------------------------------------------------------- pass1: dots (MFMA)
__global__ __launch_bounds__(256, 2) void k_pass1(
    const float* __restrict__ kbuf, const float* __restrict__ inp,
    const float* __restrict__ positions, const float* __restrict__ scales,
    const float* __restrict__ Wg,
    const _Float16* __restrict__ wh, const _Float16* __restrict__ wl,
    const float* __restrict__ b1p, const float* __restrict__ w2q,
    const float* __restrict__ qb2, float* __restrict__ dots) {
    __shared__ float wgs[128];
    int tid = threadIdx.x;
    if (tid < 32) ((float4*)wgs)[tid] = ((const float4*)Wg)[tid];
    int s = blockIdx.y, b = blockIdx.z, bs = b * SS + s;
    int wv = tid >> 6, lane = tid & 63, quad = lane >> 4, col = lane & 15;
    float p0 = positions[bs * 2], p1 = positions[bs * 2 + 1];
    float rc0 = 1.f / scales[bs * 2], rc1 = 1.f / scales[bs * 2 + 1];
    float qb = qb2[bs];
    half8 bh[8][2], bl[8][2];
    #pragma unroll
    for (int ot = 0; ot < 8; ot++)
        #pragma unroll
        for (int ks = 0; ks < 2; ks++) {
            int f = ot * 2 + ks;
            bh[ot][ks] = *(const half8*)(wh + (size_t)f * 512 + lane * 8);
            bl[ot][ks] = *(const half8*)(wl + (size_t)f * 512 + lane * 8);
        }
    float b1v[8], wqv[8];
    #pragma unroll
    for (int ot = 0; ot < 8; ot++) {
        b1v[ot] = b1p[ot * 16 + col];
        wqv[ot] = w2q[bs * DHH + ot * 16 + col];
    }
    __syncthreads();
    int rowW = blockIdx.x * 512 + wv * 128;
    for (int rt = 0; rt < 8; rt++) {
        int rowTile = rowW + rt * 16;
        half8 ah[2], al[2];
        stage_afrag(kbuf, inp, b, rowTile, quad, col, p0, p1, rc0, rc1, wgs, ah, al);
        f32x4 acc1[8], acc2[8];
        #pragma unroll
        for (int ot = 0; ot < 8; ot++) {
            acc1[ot] = (f32x4){0.f, 0.f, 0.f, 0.f};
            acc2[ot] = (f32x4){0.f, 0.f, 0.f, 0.f};
        }
        #pragma unroll
        for (int ks = 0; ks < 2; ks++) {
            #pragma unroll
            for (int ot = 0; ot < 8; ot++)
                acc1[ot] = __builtin_amdgcn_mfma_f32_16x16x32_f16(ah[ks], bh[ot][ks], acc1[ot], 0, 0, 0);
            #pragma unroll
            for (int ot = 0; ot < 8; ot++)
                acc2[ot] = __builtin_amdgcn_mfma_f32_16x16x32_f16(al[ks], bh[ot][ks], acc2[ot], 0, 0, 0);
            #pragma unroll
            for (int ot = 0; ot < 8; ot++)
                acc2[ot] = __builtin_amdgcn_mfma_f32_16x16x32_f16(ah[ks], bl[ot][ks], acc2[ot], 0, 0, 0);
        }
        float p[4] = {0.f, 0.f, 0.f, 0.f};
        #pragma unroll
        for (int ot = 0; ot < 8; ot++) {
            #pragma unroll
            for (int r = 0; r < 4; r++) {
                float h = fmaf(acc2[ot][r], LO_INV, acc1[ot][r]) + b1v[ot];
                p[r] = fmaf(fmaxf(h, 0.f), wqv[ot], p[r]);
            }
        }
        #pragma unroll
        for (int r = 0; r < 4; r++) {
            p[r] += __shfl_xor(p[r], 1, 64);
            p[r] += __shfl_xor(p[r], 2, 64);
            p[r] += __shfl_xor(p[r], 4, 64);
            p[r] += __shfl_xor(p[r], 8, 64);
        }
        if (col == 0) {
            #pragma unroll
            for (int r = 0; r < 4; r++)
                dots[((size_t)(b * NN + rowTile + quad * 4 + r)) * SS + s] = qb + p[r];
        }
    }
}

// ---------------------------------------------------------------- pass2: H (MFMA)
__global__ __launch_bounds__(256, 2) void k_pass2(
    const float* __restrict__ vbuf, const float* __restrict__ inp,
    const float* __restrict__ positions, const float* __restrict__ scales,
    const float* __restrict__ Wg,
    const _Float16* __restrict__ wh, const _Float16* __restrict__ wl,
    const float* __restrict__ b1p, const float* __restrict__ attn,
    float* __restrict__ H) {
    __shared__ float wgs[128];
    __shared__ float Hw[4 * 128];
    int tid = threadIdx.x;
    if (tid < 32) ((float4*)wgs)[tid] = ((const float4*)Wg)[tid];
    int s = blockIdx.y, b = blockIdx.z, bs = b * SS + s;
    int wv = tid >> 6, lane = tid & 63, quad = lane >> 4, col = lane & 15;
    float p0 = positions[bs * 2], p1 = positions[bs * 2 + 1];
    float rc0 = 1.f / scales[bs * 2], rc1 = 1.f / scales[bs * 2 + 1];
    half8 bh[8][2], bl[8][2];
    #pragma unroll
    for (int ot = 0; ot < 8; ot++)
        #pragma unroll
        for (int ks = 0; ks < 2; ks++) {
            int f = ot * 2 + ks;
            bh[ot][ks] = *(const half8*)(wh + (size_t)f * 512 + lane * 8);
            bl[ot][ks] = *(const half8*)(wl + (size_t)f * 512 + lane * 8);
        }
    float b1v[8];
    #pragma unroll
    for (int ot = 0; ot < 8; ot++) b1v[ot] = b1p[ot * 16 + col];
    float hq[8];
    #pragma unroll
    for (int ot = 0; ot < 8; ot++) hq[ot] = 0.f;
    __syncthreads();
    int rowW = blockIdx.x * 512 + wv * 128;
    for (int rt = 0; rt < 8; rt++) {
        int rowTile = rowW + rt * 16;
        half8 ah[2], al[2];
        stage_afrag(vbuf, inp, b, rowTile, quad, col, p0, p1, rc0, rc1, wgs, ah, al);
        float ar[4];
        #pragma unroll
        for (int r = 0; r < 4; r++)
            ar[r] = attn[((size_t)(b * NN + rowTile + quad * 4 + r)) * SS + s];
        f32x4 acc1[8], acc2[8];
        #pragma unroll
        for (int ot = 0; ot < 8; ot++) {
            acc1[ot] = (f32x4){0.f, 0.f, 0.f, 0.f};
            acc2[ot] = (f32x4){0.f, 0.f, 0.f, 0.f};
        }
        #pragma unroll
        for (int ks = 0; ks < 2; ks++) {
            #pragma unroll
            for (int ot = 0; ot < 8; ot++)
                acc1[ot] = __builtin_amdgcn_mfma_f32_16x16x32_f16(ah[ks], bh[ot][ks], acc1[ot], 0, 0, 0);
            #pragma unroll
            for (int ot = 0; ot < 8; ot++)
                acc2[ot] = __builtin_amdgcn_mfma_f32_16x16x32_f16(al[ks], bh[ot][ks], acc2[ot], 0, 0, 0);
            #pragma unroll
            for (int ot = 0; ot < 8; ot++)
                acc2[ot] = __builtin_amdgcn_mfma_f32_16x16x32_f16(ah[ks], bl[ot][ks], acc2[ot], 0, 0, 0);
        }
        #pragma unroll
        for (int ot = 0; ot < 8; ot++) {
            float t0 = 0.f;
            #pragma unroll
            for (int r = 0; r < 4; r++) {
                float h = fmaf(acc2[ot][r], LO_INV, acc1[ot][r]) + b1v[ot];
                t0 = fmaf(ar[r], fmaxf(h, 0.f), t0);
            }
            hq[ot] += t0;
        }
    }
    #pragma unroll
    for (int ot = 0; ot < 8; ot++) {
        hq[ot] += __shfl_xor(hq[ot], 16, 64);
        hq[ot] += __shfl_xor(hq[ot], 32, 64);
    }
    if (lane < 16) {
        #pragma unroll
        for (int ot = 0; ot < 8; ot++) Hw[wv * 128 + ot * 16 + lane] = hq[ot];
    }
    __syncthreads();
    if (tid < 128) {
        float hsum = Hw[tid] + Hw[128 + tid] + Hw[256 + tid] + Hw[384 + tid];
        atomicAdd(&H[bs * DHH + tid], hsum);
    }
}

// ---------------------------------------------------------------- softmax M,L per (b,s)
__global__ __launch_bounds__(256) void k_softmax_ms(
    const float* __restrict__ dots, float* __restrict__ Mv, float* __restrict__ Lv) {
    __shared__ float red[256];
    int bs = blockIdx.x;
    int b = bs >> 3, s = bs & 7;
    int t = threadIdx.x;
    const float* dp = dots + (size_t)b * NN * SS + s;
    float mx = -1e30f;
    for (int n = t; n < NN; n += 256) mx = fmaxf(mx, dp[(size_t)n * SS]);
    red[t] = mx;
    __syncthreads();
    for (int off = 128; off; off >>= 1) {
        if (t < off) red[t] = fmaxf(red[t], red[t + off]);
        __syncthreads();
    }
    float M = red[0];
    __syncthreads();
    float sm = 0.f;
    for (int n = t; n < NN; n += 256) sm += expf(dp[(size_t)n * SS] - M);
    red[t] = sm;
    __syncthreads();
    for (int off = 128; off; off >>= 1) {
        if (t < off) red[t] += red[t + off];
        __syncthreads();
    }
    if (t == 0) { Mv[bs] = M; Lv[bs] = red[0]; }
}

// ---------------------------------------------------------------- attn normalize
__global__ __launch_bounds__(256) void k_attn_norm(
    const float* __restrict__ dots, const float* __restrict__ Mv,
    const float* __restrict__ Lv, float* __restrict__ attn) {
    __shared__ float Ml[8], Rl[8];
    int b = blockIdx.x >> 4;
    int t = threadIdx.x;
    if (t < 8) { Ml[t] = Mv[b * 8 + t]; Rl[t] = 1.f / Lv[b * 8 + t]; }
    __syncthreads();
    int n = (blockIdx.x & 15) * 256 + t;
    const float* dp = dots + ((size_t)(b * NN + n)) * SS;
    float a[8];
    float rs = 0.f;
    #pragma unroll
    for (int s = 0; s < 8; s++) {
        a[s] = expf(dp[s] - Ml[s]) * Rl[s] + EPS_ATTN_F;
        rs += a[s];
    }
    float inv = 1.f / rs;
    float* ap = attn + ((size_t)(b * NN + n)) * SS;
    #pragma unroll
    for (int s = 0; s < 8; s++) ap[s] = a[s] * inv;
}

// ---------------------------------------------------------------- stats (every iter)
__global__ __launch_bounds__(256) void k_stats(
    const float* __restrict__ attn, const float* __restrict__ inp,
    float* __restrict__ stats) {
    int bs = blockIdx.x;
    int b = bs >> 3, s = bs & 7;
    int t = threadIdx.x;
    float v0 = 0.f, v1 = 0.f, v2 = 0.f, v3 = 0.f, v4 = 0.f;
    for (int n = t; n < NN; n += 256) {
        size_t rowi = (size_t)(b * NN + n);
        float a = attn[rowi * SS + s];
        float g0 = inp[rowi * CIN + 64];
        float g1 = inp[rowi * CIN + 65];
        v0 += a; v1 += a * g0; v2 += a * g1; v3 += a * g0 * g0; v4 += a * g1 * g1;
    }
    for (int off = 32; off; off >>= 1) {
        v0 += __shfl_xor(v0, off, 64); v1 += __shfl_xor(v1, off, 64);
        v2 += __shfl_xor(v2, off, 64); v3 += __shfl_xor(v3, off, 64);
        v4 += __shfl_xor(v4, off, 64);
    }
    __shared__ float red[4][5];
    if ((t & 63) == 0) {
        int w = t >> 6;
        red[w][0] = v0; red[w][1] = v1; red[w][2] = v2; red[w][3] = v3; red[w][4] = v4;
    }
    __syncthreads();
    if (t < 5) stats[bs * 5 + t] = red[0][t] + red[1][t] + red[2][t] + red[3][t];
}

// ---------------------------------------------------------------- positions/scales
__global__ void k_finalize(const float* __restrict__ stats,
                           float* __restrict__ positions, float* __restrict__ scales) {
    int bs = threadIdx.x;
    if (bs < BB * SS) {
        float A0 = stats[bs * 5 + 0];
        float A1x = stats[bs * 5 + 1], A1y = stats[bs * 5 + 2];
        float A2x = stats[bs * 5 + 3], A2y = stats[bs * 5 + 4];
        positions[bs * 2 + 0] = A1x;
        positions[bs * 2 + 1] = A1y;
        float sx = A2x - A1x * A1x * (2.f - A0);
        float sy = A2y - A1y * A1y * (2.f - A0);
        scales[bs * 2 + 0] = fminf(fmaxf(sqrtf(fmaxf(sx, 0.f)), 1e-3f), 2.f);
        scales[bs * 2 + 1] = fminf(fmaxf(sqrtf(fmaxf(sy, 0.f)), 1e-3f), 2.f);
    }
}

// ---------------------------------------------------------------- GRU + slot MLP
__global__ __launch_bounds__(64) void k_gru_mlp(
    const float* __restrict__ H, const float* __restrict__ stats,
    const float* __restrict__ W2, const float* __restrict__ b2,
    const float* __restrict__ W_ih, const float* __restrict__ W_hh,
    const float* __restrict__ b_ih, const float* __restrict__ b_hh,
    const float* __restrict__ lmg, const float* __restrict__ lmb,
    const float* __restrict__ W3, const float* __restrict__ b3,
    const float* __restrict__ W4, const float* __restrict__ b4,
    float* __restrict__ slots) {
    int bs = blockIdx.x;
    int c = threadIdx.x;
    __shared__ float hl[DHH], ul[DD], sl[DD], yl[DD], hml[DHH];
    hl[c] = H[bs * DHH + c];
    hl[c + 64] = H[bs * DHH + 64 + c];
    float hold = slots[bs * DD + c];
    sl[c] = hold;
    __syncthreads();
    float A0 = stats[bs * 5];
    float u = A0 * b2[c];
    for (int o = 0; o < DHH; o += 4) {
        float4 w = *(const float4*)(W2 + c * DHH + o);
        u = fmaf(w.x, hl[o], fmaf(w.y, hl[o + 1], fmaf(w.z, hl[o + 2], fmaf(w.w, hl[o + 3], u))));
    }
    ul[c] = u;
    __syncthreads();
    float gir = b_ih[c], giz = b_ih[64 + c], gin = b_ih[128 + c];
    float ghr = b_hh[c], ghz = b_hh[64 + c], ghn = b_hh[128 + c];
    for (int k4 = 0; k4 < DD; k4 += 4) {
        float4 uu = *(const float4*)(ul + k4);
        float4 hh = *(const float4*)(sl + k4);
        gir += dot4(uu, *(const float4*)(W_ih + c * DD + k4));
        giz += dot4(uu, *(const float4*)(W_ih + (64 + c) * DD + k4));
        gin += dot4(uu, *(const float4*)(W_ih + (128 + c) * DD + k4));
        ghr += dot4(hh, *(const float4*)(W_hh + c * DD + k4));
        ghz += dot4(hh, *(const float4*)(W_hh + (64 + c) * DD + k4));
        ghn += dot4(hh, *(const float4*)(W_hh + (128 + c) * DD + k4));
    }
    float rg = 1.f / (1.f + expf(-(gir + ghr)));
    float zg = 1.f / (1.f + expf(-(giz + ghz)));
    float ng = tanhf(gin + rg * ghn);
    float snew = (1.f - zg) * ng + zg * hold;
    float sum = snew;
    for (int off = 32; off; off >>= 1) sum += __shfl_xor(sum, off, 64);
    float m = sum * (1.f / 64.f);
    float dv = snew - m;
    float vv = dv * dv;
    for (int off = 32; off; off >>= 1) vv += __shfl_xor(vv, off, 64);
    yl[c] = dv * rsqrtf(vv * (1.f / 64.f) + LN_EPS_F) * lmg[c] + lmb[c];
    __syncthreads();
    float h0 = b3[c], h1 = b3[64 + c];
    for (int k4 = 0; k4 < DD; k4 += 4) {
        float4 yy = *(const float4*)(yl + k4);
        h0 += dot4(yy, *(const float4*)(W3 + c * DD + k4));
        h1 += dot4(yy, *(const float4*)(W3 + (64 + c) * DD + k4));
    }
    hml[c] = fmaxf(h0, 0.f);
    hml[64 + c] = fmaxf(h1, 0.f);
    __syncthreads();
    float outv = b4[c];
    for (int o4 = 0; o4 < DHH; o4 += 4) {
        float4 hm4 = *(const float4*)(hml + o4);
        outv += dot4(hm4, *(const float4*)(W4 + c * DHH + o4));
    }
    slots[bs * DD + c] = outv;
}

// ---------------------------------------------------------------- write out
__global__ __launch_bounds__(256) void k_write_out(
    const float* __restrict__ slots, const float* __restrict__ positions,
    const float* __restrict__ scales, float* __restrict__ out) {
    int tid = blockIdx.x * 256 + threadIdx.x;
    if (tid >= BB * SS * 68) return;
    int bs = tid / 68, c = tid % 68;
    float v;
    if (c < 64) v = slots[bs * 64 + c];
    else if (c < 66) v = positions[bs * 2 + (c - 64)];
    else v = scales[bs * 2 + (c - 66)];
    out[tid] = v;
}

// ---------------------------------------------------------------- launcher
extern "C" void kernel_launch(void* const* d_in, const int* in_sizes, int n_in,
                              void* d_out, int out_size, void* d_ws, size_t ws_size,
                              hipStream_t stream) {
    (void)in_sizes; (void)n_in; (void)out_size; (void)ws_size;
    const float* inp = (const float*)d_in[0];
    const float* slots_in = (const float*)d_in[1];
    const float* Wq = (const float*)d_in[2];
    const float* Wk = (const float*)d_in[3];
    const float* Wv = (const float*)d_in[4];
    const float* Wg = (const float*)d_in[5];
    const float* bg = (const float*)d_in[6];
    const float* lpg = (const float*)d_in[7];
    const float* lpb = (const float*)d_in[8];
    const float* W1 = (const float*)d_in[9];
    const float* b1 = (const float*)d_in[10];
    const float* W2 = (const float*)d_in[11];
    const float* b2 = (const float*)d_in[12];
    const float* W_ih = (const float*)d_in[13];
    const float* W_hh = (const float*)d_in[14];
    const float* b_ih = (const float*)d_in[15];
    const float* b_hh = (const float*)d_in[16];
    const float* lmg = (const float*)d_in[17];
    const float* lmb = (const float*)d_in[18];
    const float* W3 = (const float*)d_in[19];
    const float* b3 = (const float*)d_in[20];
    const float* W4 = (const float*)d_in[21];
    const float* b4 = (const float*)d_in[22];
    const float* lsg = (const float*)d_in[23];
    const float* lsb = (const float*)d_in[24];
    float* out = (float*)d_out;
    float* ws = (float*)d_ws;

    size_t o_k = 0;
    size_t o_v = o_k + (size_t)BB * NN * DD;
    size_t o_dots = o_v + (size_t)BB * NN * DD;
    size_t o_attn = o_dots + (size_t)BB * NN * SS;
    size_t o_slots = o_attn + (size_t)BB * NN * SS;
    size_t o_pos = o_slots + BB * SS * DD;
    size_t o_scl = o_pos + BB * SS * 2;
    size_t o_w2q = o_scl + BB * SS * 2;
    size_t o_qb2 = o_w2q + BB * SS * DHH;
    size_t o_M = o_qb2 + BB * SS;
    size_t o_L = o_M + BB * SS;
    size_t o_H = o_L + BB * SS;
    size_t o_stats = o_H + BB * SS * DHH;
    size_t o_wh = o_stats + BB * SS * 5;   // 16 frags * 512 halfs = 8192 halfs = 4096 floats
    size_t o_wl = o_wh + 4096;
    size_t o_b1p = o_wl + 4096;

    float* kbuf = ws + o_k;
    float* vbuf = ws + o_v;
    float* dots = ws + o_dots;
    float* attn = ws + o_attn;
    float* slots = ws + o_slots;
    float* positions = ws + o_pos;
    float* scales = ws + o_scl;
    float* w2q = ws + o_w2q;
    float* qb2 = ws + o_qb2;
    float* Mv = ws + o_M;
    float* Lv = ws + o_L;
    float* H = ws + o_H;
    float* stats = ws + o_stats;
    _Float16* wh = (_Float16*)(ws + o_wh);
    _Float16* wl = (_Float16*)(ws + o_wl);
    float* b1p = ws + o_b1p;

    k_init_slots<<<32, 256, 0, stream>>>(slots_in, slots, positions, scales);
    k_compute_kv<<<2048, 256, 0, stream>>>(inp, Wk, Wv, bg, kbuf, vbuf);
    k_w1_frag<<<4, 256, 0, stream>>>(W1, lpg, lpb, b1, wh, wl, b1p);

    for (int it = 0; it <= NITERS; ++it) {
        k_slot_prep<<<BB, 512, 0, stream>>>(slots, lsg, lsb, Wq, W2, b2, w2q, qb2);
        k_pass1<<<dim3(RB, 8, 16), 256, 0, stream>>>(kbuf, inp, positions, scales, Wg,
                                                     wh, wl, b1p, w2q, qb2, dots);
        k_softmax_ms<<<128, 256, 0, stream>>>(dots, Mv, Lv);
        k_attn_norm<<<256, 256, 0, stream>>>(dots, Mv, Lv, attn);
        if (it < NITERS) {
            hipMemsetAsync(H, 0, (size_t)BB * SS * DHH * sizeof(float), stream);
            k_pass2<<<dim3(RB, 8, 16), 256, 0, stream>>>(vbuf, inp, positions, scales, Wg,
                                                         wh, wl, b1p, attn, H);
            k_stats<<<128, 256, 0, stream>>>(attn, inp, stats);
            k_finalize<<<1, 128, 0, stream>>>(stats, positions, scales);
            k_gru_mlp<<<128, 64, 0, stream>>>(H, stats, W2, b2, W_ih, W_hh, b_ih, b_hh,
                                              lmg, lmb, W3, b3, W4, b4, slots);
        } else {
            k_stats<<<128, 256, 0, stream>>>(attn, inp, stats);
            k_finalize<<<1, 128, 0, stream>>>(stats, positions, scales);
        }
    }
    k_write_out<<<34, 256, 0, stream>>>(slots, positions, scales, out);
}

// Round 4
// 564.269 us; speedup vs baseline: 3.0402x; 1.5006x over previous
//
#include <hip/hip_runtime.h>
#include <math.h>

#define BB 16
#define NN 4096
#define SS 8
#define DD 64
#define DHH 128
#define CIN 66
#define NITERS 3
#define LN_EPS_F 1e-5f
#define EPS_ATTN_F 1e-8f
#define QSCALE 0.125f    // d^-0.5

__device__ __forceinline__ float dot4(float4 a, float4 b) {
    return fmaf(a.x, b.x, fmaf(a.y, b.y, fmaf(a.z, b.z, a.w * b.w)));
}

// ---------------------------------------------------------------- init slots
__global__ __launch_bounds__(256) void k_init_slots(
    const float* __restrict__ slots_in, float* __restrict__ slots,
    float* __restrict__ positions, float* __restrict__ scales) {
    int tid = blockIdx.x * 256 + threadIdx.x;
    if (tid < BB * SS * DD) {
        int s = (tid / DD) % SS;
        int c = tid % DD;
        slots[tid] = slots_in[s * 68 + c];
    }
    if (tid < BB * SS * 2) {
        int s = (tid >> 1) & 7;
        int p = tid & 1;
        float po = slots_in[s * 68 + 64 + p];
        positions[tid] = fminf(fmaxf(po, -1.f), 1.f);
        float sc = slots_in[s * 68 + 66 + p];
        scales[tid] = fminf(fmaxf(sc, 1e-3f), 2.f);
    }
}

// ---------------------------------------------------------------- prep W1-derived constants
// W1p[o][c] = W1[o][c]*lpg[c]; avec=W1p·wgA; bvec=W1p·wgB; s1=W1p·1;
// b1p[o] = b1[o] + sum_c W1[o][c]*lpb[c]; wgc = {mwA,mwB,AA,BB,AB2} (means)
__global__ __launch_bounds__(256) void k_prep_w(
    const float* __restrict__ W1, const float* __restrict__ lpg,
    const float* __restrict__ lpb, const float* __restrict__ b1,
    const float* __restrict__ Wg,
    float* __restrict__ W1p, float* __restrict__ avec, float* __restrict__ bvec,
    float* __restrict__ s1vec, float* __restrict__ b1p, float* __restrict__ wgc) {
    __shared__ float w1s[128 * 68];
    int tid = threadIdx.x;
    // stage W1 (8192 floats) padded
    for (int q = 0; q < 8; q++) {
        int flat = q * 1024 + tid * 4;
        int o = flat >> 6, c = flat & 63;
        *(float4*)(w1s + o * 68 + c) = *(const float4*)(W1 + flat);
    }
    __syncthreads();
    if (tid < 128) {
        int o = tid;
        float a = 0.f, bv = 0.f, s1 = 0.f, b1a = b1[o];
        for (int c = 0; c < 64; c++) {
            float w0 = w1s[o * 68 + c];
            float w = w0 * lpg[c];
            W1p[o * 64 + c] = w;
            a = fmaf(w, Wg[2 * c], a);
            bv = fmaf(w, Wg[2 * c + 1], bv);
            s1 += w;
            b1a = fmaf(w0, lpb[c], b1a);
        }
        avec[o] = a; bvec[o] = bv; s1vec[o] = s1; b1p[o] = b1a;
    }
    if (tid == 128) {
        float mwA = 0.f, mwB = 0.f, AA = 0.f, BBv = 0.f, AB = 0.f;
        for (int c = 0; c < 64; c++) {
            float wa = Wg[2 * c], wb = Wg[2 * c + 1];
            mwA += wa; mwB += wb;
            AA = fmaf(wa, wa, AA); BBv = fmaf(wb, wb, BBv); AB = fmaf(wa, wb, AB);
        }
        wgc[0] = mwA * (1.f / 64.f);
        wgc[1] = mwB * (1.f / 64.f);
        wgc[2] = AA * (1.f / 64.f);
        wgc[3] = BBv * (1.f / 64.f);
        wgc[4] = AB * (2.f / 64.f);
    }
}

// ---------------------------------------------------------------- fused kv + U + moments
// Per 64-row block: k = Wk f + bg, v = Wv f + bg (registers), row moments ->
// kaux/vaux, then uk = W1p k, uv = W1p v via LDS-sequenced tiles.
__global__ __launch_bounds__(512) void k_prep_kvu(
    const float* __restrict__ inp, const float* __restrict__ Wk,
    const float* __restrict__ Wv, const float* __restrict__ bg,
    const float* __restrict__ W1p, const float* __restrict__ Wg,
    float* __restrict__ uk, float* __restrict__ uv,
    float* __restrict__ kaux, float* __restrict__ vaux, float* __restrict__ gbuf) {
    __shared__ float sm[13316];
    float* A = sm;            // 4352: feats -> kc -> vc  (64 x 68)
    float* Bw = sm + 4352;    // 8704: Wk|Wv -> W1p       (128 x 68)
    float* wg2 = sm + 13056;  // 132: wgA[0..63], wgB at +66
    float* gc = sm + 13188;   // 128
    int tid = threadIdx.x;
    int rowBase = blockIdx.x * 64;
    int r = tid >> 3, j = tid & 7;
    {   // stage feats cols 0..63 (float2, row stride 66)
        const float* src = inp + (size_t)(rowBase + r) * CIN + j * 8;
        float* dst = A + r * 68 + j * 8;
        #pragma unroll
        for (int q = 0; q < 4; q++) {
            float2 t = *(const float2*)(src + 2 * q);
            dst[2 * q] = t.x; dst[2 * q + 1] = t.y;
        }
    }
    if (tid < 64) {
        float2 g = *(const float2*)(inp + (size_t)(rowBase + tid) * CIN + 64);
        gc[tid * 2] = g.x; gc[tid * 2 + 1] = g.y;
        *(float2*)(gbuf + (size_t)(rowBase + tid) * 2) = g;
    } else if (tid < 128) {
        int c = tid - 64;
        wg2[c] = Wg[2 * c]; wg2[66 + c] = Wg[2 * c + 1];
    }
    {   // stage Wk, Wv padded
        int flat = tid * 8;
        int o = flat >> 6, c = flat & 63;
        *(float4*)(Bw + o * 68 + c) = *(const float4*)(Wk + flat);
        *(float4*)(Bw + o * 68 + c + 4) = *(const float4*)(Wk + flat + 4);
        *(float4*)(Bw + (o + 64) * 68 + c) = *(const float4*)(Wv + flat);
        *(float4*)(Bw + (o + 64) * 68 + c + 4) = *(const float4*)(Wv + flat + 4);
    }
    __syncthreads();
    // phase 1: k,v in registers (outs o = 8i+j of row r), bg folded in
    float ak[8], av[8];
    #pragma unroll
    for (int i = 0; i < 8; i++) { float bgi = bg[8 * i + j]; ak[i] = bgi; av[i] = bgi; }
    for (int c4 = 0; c4 < 64; c4 += 4) {
        float4 x4 = *(const float4*)(A + r * 68 + c4);
        #pragma unroll
        for (int i = 0; i < 8; i++) {
            ak[i] += dot4(x4, *(const float4*)(Bw + (8 * i + j) * 68 + c4));
            av[i] += dot4(x4, *(const float4*)(Bw + (64 + 8 * i + j) * 68 + c4));
        }
    }
    // moments (channel index of ak[i] is 8i+j)
    float mk = 0.f, kk = 0.f, kA = 0.f, kB = 0.f;
    float mv = 0.f, vvm = 0.f, vA = 0.f, vB = 0.f;
    #pragma unroll
    for (int i = 0; i < 8; i++) {
        float wa = wg2[8 * i + j], wb = wg2[66 + 8 * i + j];
        float x = ak[i];
        mk += x; kk = fmaf(x, x, kk); kA = fmaf(x, wa, kA); kB = fmaf(x, wb, kB);
        x = av[i];
        mv += x; vvm = fmaf(x, x, vvm); vA = fmaf(x, wa, vA); vB = fmaf(x, wb, vB);
    }
    #pragma unroll
    for (int off = 1; off <= 4; off <<= 1) {
        mk += __shfl_xor(mk, off, 64); kk += __shfl_xor(kk, off, 64);
        kA += __shfl_xor(kA, off, 64); kB += __shfl_xor(kB, off, 64);
        mv += __shfl_xor(mv, off, 64); vvm += __shfl_xor(vvm, off, 64);
        vA += __shfl_xor(vA, off, 64); vB += __shfl_xor(vB, off, 64);
    }
    if (j == 0) {
        size_t rg = (size_t)(rowBase + r);
        float g0 = gc[2 * r], g1 = gc[2 * r + 1];
        float4 m1 = {mk * (1.f / 64.f), kk * (1.f / 64.f), kA * (1.f / 32.f), kB * (1.f / 32.f)};
        float4 m2 = {g0, g1, 0.f, 0.f};
        *(float4*)(kaux + rg * 8) = m1;
        *(float4*)(kaux + rg * 8 + 4) = m2;
        float4 n1 = {mv * (1.f / 64.f), vvm * (1.f / 64.f), vA * (1.f / 32.f), vB * (1.f / 32.f)};
        *(float4*)(vaux + rg * 8) = n1;
        *(float4*)(vaux + rg * 8 + 4) = m2;
    }
    __syncthreads();   // feats & Wk/Wv reads done
    // store kc over A; stage W1p over Bw
    #pragma unroll
    for (int i = 0; i < 8; i++) A[r * 68 + 8 * i + j] = ak[i];
    {
        int flat = tid * 16;
        int o = flat >> 6, c = flat & 63;
        #pragma unroll
        for (int q = 0; q < 4; q++)
            *(float4*)(Bw + o * 68 + c + 4 * q) = *(const float4*)(W1p + flat + 4 * q);
    }
    __syncthreads();
    // phase 2a: uk = W1p kc ; outs o = j*4 + 32*i + s
    {
        float acc[4][4];
        #pragma unroll
        for (int i = 0; i < 4; i++)
            #pragma unroll
            for (int s = 0; s < 4; s++) acc[i][s] = 0.f;
        for (int c4 = 0; c4 < 64; c4 += 4) {
            float4 x4 = *(const float4*)(A + r * 68 + c4);
            #pragma unroll
            for (int i = 0; i < 4; i++)
                #pragma unroll
                for (int s = 0; s < 4; s++)
                    acc[i][s] += dot4(x4, *(const float4*)(Bw + (j * 4 + 32 * i + s) * 68 + c4));
        }
        #pragma unroll
        for (int i = 0; i < 4; i++) {
            float4 st = {acc[i][0], acc[i][1], acc[i][2], acc[i][3]};
            *(float4*)(uk + (size_t)(rowBase + r) * 128 + j * 4 + 32 * i) = st;
        }
    }
    __syncthreads();   // kc reads done
    #pragma unroll
    for (int i = 0; i < 8; i++) A[r * 68 + 8 * i + j] = av[i];
    __syncthreads();
    // phase 2b: uv
    {
        float acc[4][4];
        #pragma unroll
        for (int i = 0; i < 4; i++)
            #pragma unroll
            for (int s = 0; s < 4; s++) acc[i][s] = 0.f;
        for (int c4 = 0; c4 < 64; c4 += 4) {
            float4 x4 = *(const float4*)(A + r * 68 + c4);
            #pragma unroll
            for (int i = 0; i < 4; i++)
                #pragma unroll
                for (int s = 0; s < 4; s++)
                    acc[i][s] += dot4(x4, *(const float4*)(Bw + (j * 4 + 32 * i + s) * 68 + c4));
        }
        #pragma unroll
        for (int i = 0; i < 4; i++) {
            float4 st = {acc[i][0], acc[i][1], acc[i][2], acc[i][3]};
            *(float4*)(uv + (size_t)(rowBase + r) * 128 + j * 4 + 32 * i) = st;
        }
    }
}

// ---------------------------------------------------------------- slot_prep: w2q, qb2
__global__ __launch_bounds__(512) void k_slot_prep(
    const float* __restrict__ slots, const float* __restrict__ lsg,
    const float* __restrict__ lsb, const float* __restrict__ Wq,
    const float* __restrict__ W2, const float* __restrict__ b2,
    float* __restrict__ w2q, float* __restrict__ qb2) {
    __shared__ float sn[512];
    __shared__ float qv[SS][64];
    __shared__ float wsum[8], wsum2[8];
    int b = blockIdx.x, t = threadIdx.x;
    int s = t >> 6, c = t & 63;
    float x = slots[(b * SS + s) * DD + c];
    float sum = x;
    for (int off = 32; off; off >>= 1) sum += __shfl_xor(sum, off, 64);
    float m = sum * (1.f / 64.f);
    float dv = x - m;
    float vs = dv * dv;
    for (int off = 32; off; off >>= 1) vs += __shfl_xor(vs, off, 64);
    float y = dv * rsqrtf(vs * (1.f / 64.f) + LN_EPS_F) * lsg[c] + lsb[c];
    float s1 = y, s2 = y * y;
    for (int off = 32; off; off >>= 1) { s1 += __shfl_xor(s1, off, 64); s2 += __shfl_xor(s2, off, 64); }
    if (c == 0) { wsum[s] = s1; wsum2[s] = s2; }
    __syncthreads();
    float ts1 = 0.f, ts2 = 0.f;
    #pragma unroll
    for (int i = 0; i < 8; i++) { ts1 += wsum[i]; ts2 += wsum2[i]; }
    float gm = ts1 * (1.f / 512.f);
    float gv = ts2 * (1.f / 512.f) - gm * gm;
    sn[t] = (y - gm) * rsqrtf(gv + LN_EPS_F);
    __syncthreads();
    float acc = 0.f;
    for (int j4 = 0; j4 < 64; j4 += 4)
        acc += dot4(*(const float4*)&sn[s * 64 + j4], *(const float4*)(Wq + c * 64 + j4));
    qv[s][c] = acc;
    __syncthreads();
    float a0 = 0.f, a1 = 0.f;
    for (int cc = 0; cc < 64; cc++) {
        float qc = qv[s][cc];
        a0 = fmaf(qc, W2[cc * DHH + c], a0);
        a1 = fmaf(qc, W2[cc * DHH + c + 64], a1);
    }
    w2q[(b * SS + s) * DHH + c] = a0 * QSCALE;
    w2q[(b * SS + s) * DHH + c + 64] = a1 * QSCALE;
    float qb = qv[s][c] * b2[c];
    for (int off = 32; off; off >>= 1) qb += __shfl_xor(qb, off, 64);
    if (c == 0) qb2[b * SS + s] = qb * QSCALE;
}

// ---------------------------------------------------------------- pass1: dots (linearized)
__global__ __launch_bounds__(256) void k_pass1(
    const float* __restrict__ uk, const float* __restrict__ kaux,
    const float* __restrict__ positions, const float* __restrict__ scales,
    const float* __restrict__ avec, const float* __restrict__ bvec,
    const float* __restrict__ s1vec, const float* __restrict__ b1p,
    const float* __restrict__ wgc, const float* __restrict__ w2q,
    const float* __restrict__ qb2, float* __restrict__ dots) {
    int tid = threadIdx.x;
    int chunk = blockIdx.x, b = blockIdx.y;
    int wv = tid >> 6, lane = tid & 63, rh = lane >> 5, ol = lane & 31;
    int o4 = ol * 4;
    float4 a4 = *(const float4*)(avec + o4);
    float4 bv4 = *(const float4*)(bvec + o4);
    float4 s14 = *(const float4*)(s1vec + o4);
    float4 b14 = *(const float4*)(b1p + o4);
    float mwA = wgc[0], mwB = wgc[1], AA = wgc[2], BBc = wgc[3], AB2 = wgc[4];
    float p0[8], p1[8], rc0[8], rc1[8], qb[8];
    float4 wq[8];
    #pragma unroll
    for (int s = 0; s < 8; s++) {
        int bs = b * 8 + s;
        p0[s] = positions[bs * 2]; p1[s] = positions[bs * 2 + 1];
        rc0[s] = 1.f / scales[bs * 2]; rc1[s] = 1.f / scales[bs * 2 + 1];
        qb[s] = qb2[bs];
        wq[s] = *(const float4*)(w2q + (size_t)bs * DHH + o4);
    }
    int row0 = chunk * 128 + wv * 32;
    for (int st = 0; st < 16; st++) {
        int row = row0 + st * 2 + rh;
        size_t rg = (size_t)b * NN + row;
        float4 m1 = *(const float4*)(kaux + rg * 8);
        float4 m2 = *(const float4*)(kaux + rg * 8 + 4);
        float4 u4 = *(const float4*)(uk + rg * 128 + o4);
        #pragma unroll
        for (int s = 0; s < 8; s++) {
            float rel0 = (m2.x - p0[s]) * rc0[s];
            float rel1 = (m2.y - p1[s]) * rc1[s];
            float m = fmaf(rel1, mwB, fmaf(rel0, mwA, m1.x));
            float q2 = fmaf(rel0, fmaf(rel0, AA, m1.z), m1.y);
            q2 = fmaf(rel1, fmaf(rel1, BBc, m1.w), q2);
            q2 = fmaf(rel0 * rel1, AB2, q2);
            float var = fmaf(-m, m, q2);
            float rstd = rsqrtf(fmaxf(var, 0.f) + LN_EPS_F);
            float p = 0.f, t, h;
            t = fmaf(-m, s14.x, u4.x); t = fmaf(rel0, a4.x, t); t = fmaf(rel1, bv4.x, t);
            h = fmaf(rstd, t, b14.x); p = fmaf(fmaxf(h, 0.f), wq[s].x, p);
            t = fmaf(-m, s14.y, u4.y); t = fmaf(rel0, a4.y, t); t = fmaf(rel1, bv4.y, t);
            h = fmaf(rstd, t, b14.y); p = fmaf(fmaxf(h, 0.f), wq[s].y, p);
            t = fmaf(-m, s14.z, u4.z); t = fmaf(rel0, a4.z, t); t = fmaf(rel1, bv4.z, t);
            h = fmaf(rstd, t, b14.z); p = fmaf(fmaxf(h, 0.f), wq[s].z, p);
            t = fmaf(-m, s14.w, u4.w); t = fmaf(rel0, a4.w, t); t = fmaf(rel1, bv4.w, t);
            h = fmaf(rstd, t, b14.w); p = fmaf(fmaxf(h, 0.f), wq[s].w, p);
            p += __shfl_xor(p, 1, 64);
            p += __shfl_xor(p, 2, 64);
            p += __shfl_xor(p, 4, 64);
            p += __shfl_xor(p, 8, 64);
            p += __shfl_xor(p, 16, 64);
            if (ol == 0)
                dots[(size_t)(b * 8 + s) * NN + row] = p + qb[s];
        }
    }
}

// ---------------------------------------------------------------- pass2: H (linearized)
__global__ __launch_bounds__(256) void k_pass2(
    const float* __restrict__ uv, const float* __restrict__ vaux,
    const float* __restrict__ positions, const float* __restrict__ scales,
    const float* __restrict__ avec, const float* __restrict__ bvec,
    const float* __restrict__ s1vec, const float* __restrict__ b1p,
    const float* __restrict__ wgc, const float* __restrict__ attn,
    float* __restrict__ H) {
    __shared__ float Hw[4 * 1024];
    int tid = threadIdx.x;
    int chunk = blockIdx.x, b = blockIdx.y;
    int wv = tid >> 6, lane = tid & 63, rh = lane >> 5, ol = lane & 31;
    int o4 = ol * 4;
    float4 a4 = *(const float4*)(avec + o4);
    float4 bv4 = *(const float4*)(bvec + o4);
    float4 s14 = *(const float4*)(s1vec + o4);
    float4 b14 = *(const float4*)(b1p + o4);
    float mwA = wgc[0], mwB = wgc[1], AA = wgc[2], BBc = wgc[3], AB2 = wgc[4];
    float p0[8], p1[8], rc0[8], rc1[8];
    #pragma unroll
    for (int s = 0; s < 8; s++) {
        int bs = b * 8 + s;
        p0[s] = positions[bs * 2]; p1[s] = positions[bs * 2 + 1];
        rc0[s] = 1.f / scales[bs * 2]; rc1[s] = 1.f / scales[bs * 2 + 1];
    }
    float hq[8][4];
    #pragma unroll
    for (int s = 0; s < 8; s++)
        #pragma unroll
        for (int c = 0; c < 4; c++) hq[s][c] = 0.f;
    int row0 = chunk * 128 + wv * 32;
    for (int st = 0; st < 16; st++) {
        int row = row0 + st * 2 + rh;
        size_t rg = (size_t)b * NN + row;
        float4 m1 = *(const float4*)(vaux + rg * 8);
        float4 m2 = *(const float4*)(vaux + rg * 8 + 4);
        float4 u4 = *(const float4*)(uv + rg * 128 + o4);
        #pragma unroll
        for (int s = 0; s < 8; s++) {
            float ar = attn[(size_t)(b * 8 + s) * NN + row];
            float rel0 = (m2.x - p0[s]) * rc0[s];
            float rel1 = (m2.y - p1[s]) * rc1[s];
            float m = fmaf(rel1, mwB, fmaf(rel0, mwA, m1.x));
            float q2 = fmaf(rel0, fmaf(rel0, AA, m1.z), m1.y);
            q2 = fmaf(rel1, fmaf(rel1, BBc, m1.w), q2);
            q2 = fmaf(rel0 * rel1, AB2, q2);
            float var = fmaf(-m, m, q2);
            float rstd = rsqrtf(fmaxf(var, 0.f) + LN_EPS_F);
            float t, h;
            t = fmaf(-m, s14.x, u4.x); t = fmaf(rel0, a4.x, t); t = fmaf(rel1, bv4.x, t);
            h = fmaf(rstd, t, b14.x); hq[s][0] = fmaf(ar, fmaxf(h, 0.f), hq[s][0]);
            t = fmaf(-m, s14.y, u4.y); t = fmaf(rel0, a4.y, t); t = fmaf(rel1, bv4.y, t);
            h = fmaf(rstd, t, b14.y); hq[s][1] = fmaf(ar, fmaxf(h, 0.f), hq[s][1]);
            t = fmaf(-m, s14.z, u4.z); t = fmaf(rel0, a4.z, t); t = fmaf(rel1, bv4.z, t);
            h = fmaf(rstd, t, b14.z); hq[s][2] = fmaf(ar, fmaxf(h, 0.f), hq[s][2]);
            t = fmaf(-m, s14.w, u4.w); t = fmaf(rel0, a4.w, t); t = fmaf(rel1, bv4.w, t);
            h = fmaf(rstd, t, b14.w); hq[s][3] = fmaf(ar, fmaxf(h, 0.f), hq[s][3]);
        }
    }
    #pragma unroll
    for (int s = 0; s < 8; s++)
        #pragma unroll
        for (int c = 0; c < 4; c++)
            hq[s][c] += __shfl_xor(hq[s][c], 32, 64);
    if (lane < 32) {
        #pragma unroll
        for (int s = 0; s < 8; s++) {
            float4 st = {hq[s][0], hq[s][1], hq[s][2], hq[s][3]};
            *(float4*)(Hw + wv * 1024 + s * 128 + o4) = st;
        }
    }
    __syncthreads();
    #pragma unroll
    for (int q = 0; q < 4; q++) {
        int flat = q * 256 + tid;       // flat = s*128 + o
        float sum = Hw[flat] + Hw[1024 + flat] + Hw[2048 + flat] + Hw[3072 + flat];
        atomicAdd(&H[(size_t)b * 8 * DHH + flat], sum);
    }
}

// ---------------------------------------------------------------- softmax M,L per (b,s)
__global__ __launch_bounds__(256) void k_softmax_ms(
    const float* __restrict__ dots, float* __restrict__ Mv, float* __restrict__ Lv) {
    __shared__ float red[4];
    int bs = blockIdx.x, t = threadIdx.x;
    const float* dp = dots + (size_t)bs * NN;
    float mx = -1e30f;
    #pragma unroll
    for (int it = 0; it < 4; it++) {
        float4 d = *(const float4*)(dp + it * 1024 + t * 4);
        mx = fmaxf(mx, fmaxf(fmaxf(d.x, d.y), fmaxf(d.z, d.w)));
    }
    for (int off = 32; off; off >>= 1) mx = fmaxf(mx, __shfl_xor(mx, off, 64));
    if ((t & 63) == 0) red[t >> 6] = mx;
    __syncthreads();
    float M = fmaxf(fmaxf(red[0], red[1]), fmaxf(red[2], red[3]));
    __syncthreads();
    float sm = 0.f;
    #pragma unroll
    for (int it = 0; it < 4; it++) {
        float4 d = *(const float4*)(dp + it * 1024 + t * 4);
        sm += expf(d.x - M) + expf(d.y - M) + expf(d.z - M) + expf(d.w - M);
    }
    for (int off = 32; off; off >>= 1) sm += __shfl_xor(sm, off, 64);
    if ((t & 63) == 0) red[t >> 6] = sm;
    __syncthreads();
    if (t == 0) { Mv[bs] = M; Lv[bs] = red[0] + red[1] + red[2] + red[3]; }
}

// ---------------------------------------------------------------- attn normalize
__global__ __launch_bounds__(256) void k_attn(
    const float* __restrict__ dots, const float* __restrict__ Mv,
    const float* __restrict__ Lv, float* __restrict__ attn) {
    int chunk = blockIdx.x, b = blockIdx.y;
    int n = chunk * 256 + threadIdx.x;
    float a[8];
    float rs = 0.f;
    #pragma unroll
    for (int s = 0; s < 8; s++) {
        int bs = b * 8 + s;
        float d = dots[(size_t)bs * NN + n];
        a[s] = expf(d - Mv[bs]) * (1.f / Lv[bs]) + EPS_ATTN_F;
        rs += a[s];
    }
    float inv = 1.f / rs;
    #pragma unroll
    for (int s = 0; s < 8; s++)
        attn[(size_t)(b * 8 + s) * NN + n] = a[s] * inv;
}

// ---------------------------------------------------------------- stats + finalize
__global__ __launch_bounds__(256) void k_stats(
    const float* __restrict__ attn, const float* __restrict__ gbuf,
    float* __restrict__ positions, float* __restrict__ scales,
    float* __restrict__ stats) {
    __shared__ float red[4][5];
    int bs = blockIdx.x, b = bs >> 3, t = threadIdx.x;
    const float* ap = attn + (size_t)bs * NN;
    const float* gb = gbuf + (size_t)b * NN * 2;
    float v0 = 0.f, v1 = 0.f, v2 = 0.f, v3 = 0.f, v4 = 0.f;
    #pragma unroll
    for (int it = 0; it < 4; it++) {
        int n0 = it * 1024 + t * 4;
        float4 av = *(const float4*)(ap + n0);
        float4 g1 = *(const float4*)(gb + (size_t)n0 * 2);
        float4 g2 = *(const float4*)(gb + (size_t)n0 * 2 + 4);
        v0 += av.x + av.y + av.z + av.w;
        v1 = fmaf(av.x, g1.x, fmaf(av.y, g1.z, fmaf(av.z, g2.x, fmaf(av.w, g2.z, v1))));
        v2 = fmaf(av.x, g1.y, fmaf(av.y, g1.w, fmaf(av.z, g2.y, fmaf(av.w, g2.w, v2))));
        v3 = fmaf(av.x, g1.x * g1.x, fmaf(av.y, g1.z * g1.z, fmaf(av.z, g2.x * g2.x, fmaf(av.w, g2.z * g2.z, v3))));
        v4 = fmaf(av.x, g1.y * g1.y, fmaf(av.y, g1.w * g1.w, fmaf(av.z, g2.y * g2.y, fmaf(av.w, g2.w * g2.w, v4))));
    }
    for (int off = 32; off; off >>= 1) {
        v0 += __shfl_xor(v0, off, 64); v1 += __shfl_xor(v1, off, 64);
        v2 += __shfl_xor(v2, off, 64); v3 += __shfl_xor(v3, off, 64);
        v4 += __shfl_xor(v4, off, 64);
    }
    if ((t & 63) == 0) {
        int w = t >> 6;
        red[w][0] = v0; red[w][1] = v1; red[w][2] = v2; red[w][3] = v3; red[w][4] = v4;
    }
    __syncthreads();
    if (t == 0) {
        float A0 = red[0][0] + red[1][0] + red[2][0] + red[3][0];
        float A1x = red[0][1] + red[1][1] + red[2][1] + red[3][1];
        float A1y = red[0][2] + red[1][2] + red[2][2] + red[3][2];
        float A2x = red[0][3] + red[1][3] + red[2][3] + red[3][3];
        float A2y = red[0][4] + red[1][4] + red[2][4] + red[3][4];
        positions[bs * 2 + 0] = A1x;
        positions[bs * 2 + 1] = A1y;
        float sx = A2x - A1x * A1x * (2.f - A0);
        float sy = A2y - A1y * A1y * (2.f - A0);
        scales[bs * 2 + 0] = fminf(fmaxf(sqrtf(fmaxf(sx, 0.f)), 1e-3f), 2.f);
        scales[bs * 2 + 1] = fminf(fmaxf(sqrtf(fmaxf(sy, 0.f)), 1e-3f), 2.f);
        stats[bs] = A0;
    }
}

// ---------------------------------------------------------------- GRU + slot MLP
__global__ __launch_bounds__(64) void k_gru_mlp(
    const float* __restrict__ H, const float* __restrict__ stats,
    const float* __restrict__ W2, const float* __restrict__ b2,
    const float* __restrict__ W_ih, const float* __restrict__ W_hh,
    const float* __restrict__ b_ih, const float* __restrict__ b_hh,
    const float* __restrict__ lmg, const float* __restrict__ lmb,
    const float* __restrict__ W3, const float* __restrict__ b3,
    const float* __restrict__ W4, const float* __restrict__ b4,
    float* __restrict__ slots) {
    int bs = blockIdx.x;
    int c = threadIdx.x;
    __shared__ float hl[DHH], ul[DD], sl[DD], yl[DD], hml[DHH];
    hl[c] = H[bs * DHH + c];
    hl[c + 64] = H[bs * DHH + 64 + c];
    float hold = slots[bs * DD + c];
    sl[c] = hold;
    __syncthreads();
    float A0 = stats[bs];
    float u = A0 * b2[c];
    for (int o = 0; o < DHH; o += 4) {
        float4 w = *(const float4*)(W2 + c * DHH + o);
        u = fmaf(w.x, hl[o], fmaf(w.y, hl[o + 1], fmaf(w.z, hl[o + 2], fmaf(w.w, hl[o + 3], u))));
    }
    ul[c] = u;
    __syncthreads();
    float gir = b_ih[c], giz = b_ih[64 + c], gin = b_ih[128 + c];
    float ghr = b_hh[c], ghz = b_hh[64 + c], ghn = b_hh[128 + c];
    for (int k4 = 0; k4 < DD; k4 += 4) {
        float4 uu = *(const float4*)(ul + k4);
        float4 hh = *(const float4*)(sl + k4);
        gir += dot4(uu, *(const float4*)(W_ih + c * DD + k4));
        giz += dot4(uu, *(const float4*)(W_ih + (64 + c) * DD + k4));
        gin += dot4(uu, *(const float4*)(W_ih + (128 + c) * DD + k4));
        ghr += dot4(hh, *(const float4*)(W_hh + c * DD + k4));
        ghz += dot4(hh, *(const float4*)(W_hh + (64 + c) * DD + k4));
        ghn += dot4(hh, *(const float4*)(W_hh + (128 + c) * DD + k4));
    }
    float rg = 1.f / (1.f + expf(-(gir + ghr)));
    float zg = 1.f / (1.f + expf(-(giz + ghz)));
    float ng = tanhf(gin + rg * ghn);
    float snew = (1.f - zg) * ng + zg * hold;
    float sum = snew;
    for (int off = 32; off; off >>= 1) sum += __shfl_xor(sum, off, 64);
    float m = sum * (1.f / 64.f);
    float dv = snew - m;
    float vv = dv * dv;
    for (int off = 32; off; off >>= 1) vv += __shfl_xor(vv, off, 64);
    yl[c] = dv * rsqrtf(vv * (1.f / 64.f) + LN_EPS_F) * lmg[c] + lmb[c];
    __syncthreads();
    float h0 = b3[c], h1 = b3[64 + c];
    for (int k4 = 0; k4 < DD; k4 += 4) {
        float4 yy = *(const float4*)(yl + k4);
        h0 += dot4(yy, *(const float4*)(W3 + c * DD + k4));
        h1 += dot4(yy, *(const float4*)(W3 + (64 + c) * DD + k4));
    }
    hml[c] = fmaxf(h0, 0.f);
    hml[64 + c] = fmaxf(h1, 0.f);
    __syncthreads();
    float outv = b4[c];
    for (int o4 = 0; o4 < DHH; o4 += 4) {
        float4 hm4 = *(const float4*)(hml + o4);
        outv += dot4(hm4, *(const float4*)(W4 + c * DHH + o4));
    }
    slots[bs * DD + c] = outv;
}

// ---------------------------------------------------------------- write out
__global__ __launch_bounds__(256) void k_write_out(
    const float* __restrict__ slots, const float* __restrict__ positions,
    const float* __restrict__ scales, float* __restrict__ out) {
    int tid = blockIdx.x * 256 + threadIdx.x;
    if (tid >= BB * SS * 68) return;
    int bs = tid / 68, c = tid % 68;
    float v;
    if (c < 64) v = slots[bs * 64 + c];
    else if (c < 66) v = positions[bs * 2 + (c - 64)];
    else v = scales[bs * 2 + (c - 66)];
    out[tid] = v;
}

// ---------------------------------------------------------------- launcher
extern "C" void kernel_launch(void* const* d_in, const int* in_sizes, int n_in,
                              void* d_out, int out_size, void* d_ws, size_t ws_size,
                              hipStream_t stream) {
    (void)in_sizes; (void)n_in; (void)out_size; (void)ws_size;
    const float* inp = (const float*)d_in[0];
    const float* slots_in = (const float*)d_in[1];
    const float* Wq = (const float*)d_in[2];
    const float* Wk = (const float*)d_in[3];
    const float* Wv = (const float*)d_in[4];
    const float* Wg = (const float*)d_in[5];
    const float* bg = (const float*)d_in[6];
    const float* lpg = (const float*)d_in[7];
    const float* lpb = (const float*)d_in[8];
    const float* W1 = (const float*)d_in[9];
    const float* b1 = (const float*)d_in[10];
    const float* W2 = (const float*)d_in[11];
    const float* b2 = (const float*)d_in[12];
    const float* W_ih = (const float*)d_in[13];
    const float* W_hh = (const float*)d_in[14];
    const float* b_ih = (const float*)d_in[15];
    const float* b_hh = (const float*)d_in[16];
    const float* lmg = (const float*)d_in[17];
    const float* lmb = (const float*)d_in[18];
    const float* W3 = (const float*)d_in[19];
    const float* b3 = (const float*)d_in[20];
    const float* W4 = (const float*)d_in[21];
    const float* b4 = (const float*)d_in[22];
    const float* lsg = (const float*)d_in[23];
    const float* lsb = (const float*)d_in[24];
    float* out = (float*)d_out;
    float* ws = (float*)d_ws;

    const size_t NR = (size_t)BB * NN;          // 65536 rows
    size_t o_uk = 0;
    size_t o_uv = o_uk + NR * 128;
    size_t o_kaux = o_uv + NR * 128;
    size_t o_vaux = o_kaux + NR * 8;
    size_t o_gbuf = o_vaux + NR * 8;
    size_t o_dots = o_gbuf + NR * 2;
    size_t o_attn = o_dots + NR * SS;
    size_t o_slots = o_attn + NR * SS;
    size_t o_pos = o_slots + BB * SS * DD;
    size_t o_scl = o_pos + BB * SS * 2;
    size_t o_w2q = o_scl + BB * SS * 2;
    size_t o_qb2 = o_w2q + BB * SS * DHH;
    size_t o_Mv = o_qb2 + BB * SS;
    size_t o_Lv = o_Mv + BB * SS;
    size_t o_H = o_Lv + BB * SS;
    size_t o_stats = o_H + BB * SS * DHH;
    size_t o_W1p = o_stats + BB * SS;
    size_t o_avec = o_W1p + DHH * DD;
    size_t o_bvec = o_avec + DHH;
    size_t o_s1v = o_bvec + DHH;
    size_t o_b1p = o_s1v + DHH;
    size_t o_wgc = o_b1p + DHH;

    float* uk = ws + o_uk;
    float* uv = ws + o_uv;
    float* kaux = ws + o_kaux;
    float* vaux = ws + o_vaux;
    float* gbuf = ws + o_gbuf;
    float* dots = ws + o_dots;
    float* attn = ws + o_attn;
    float* slots = ws + o_slots;
    float* positions = ws + o_pos;
    float* scales = ws + o_scl;
    float* w2q = ws + o_w2q;
    float* qb2 = ws + o_qb2;
    float* Mv = ws + o_Mv;
    float* Lv = ws + o_Lv;
    float* H = ws + o_H;
    float* stats = ws + o_stats;
    float* W1p = ws + o_W1p;
    float* avec = ws + o_avec;
    float* bvec = ws + o_bvec;
    float* s1v = ws + o_s1v;
    float* b1p = ws + o_b1p;
    float* wgc = ws + o_wgc;

    k_init_slots<<<32, 256, 0, stream>>>(slots_in, slots, positions, scales);
    k_prep_w<<<1, 256, 0, stream>>>(W1, lpg, lpb, b1, Wg, W1p, avec, bvec, s1v, b1p, wgc);
    k_prep_kvu<<<1024, 512, 0, stream>>>(inp, Wk, Wv, bg, W1p, Wg, uk, uv, kaux, vaux, gbuf);

    for (int it = 0; it <= NITERS; ++it) {
        k_slot_prep<<<BB, 512, 0, stream>>>(slots, lsg, lsb, Wq, W2, b2, w2q, qb2);
        k_pass1<<<dim3(32, BB), 256, 0, stream>>>(uk, kaux, positions, scales,
                                                  avec, bvec, s1v, b1p, wgc, w2q, qb2, dots);
        k_softmax_ms<<<BB * SS, 256, 0, stream>>>(dots, Mv, Lv);
        k_attn<<<dim3(16, BB), 256, 0, stream>>>(dots, Mv, Lv, attn);
        if (it < NITERS) {
            hipMemsetAsync(H, 0, (size_t)BB * SS * DHH * sizeof(float), stream);
            k_pass2<<<dim3(32, BB), 256, 0, stream>>>(uv, vaux, positions, scales,
                                                      avec, bvec, s1v, b1p, wgc, attn, H);
            k_stats<<<BB * SS, 256, 0, stream>>>(attn, gbuf, positions, scales, stats);
            k_gru_mlp<<<BB * SS, 64, 0, stream>>>(H, stats, W2, b2, W_ih, W_hh, b_ih, b_hh,
                                                  lmg, lmb, W3, b3, W4, b4, slots);
        } else {
            k_stats<<<BB * SS, 256, 0, stream>>>(attn, gbuf, positions, scales, stats);
        }
    }
    k_write_out<<<34, 256, 0, stream>>>(slots, positions, scales, out);
}

// Round 5
// 474.947 us; speedup vs baseline: 3.6119x; 1.1881x over previous
//
#include <hip/hip_runtime.h>
#include <math.h>

#define BB 16
#define NN 4096
#define SS 8
#define DD 64
#define DHH 128
#define CIN 66
#define NITERS 3
#define LN_EPS_F 1e-5f
#define EPS_ATTN_F 1e-8f
#define QSCALE 0.125f    // d^-0.5

__device__ __forceinline__ float dot4(float4 a, float4 b) {
    return fmaf(a.x, b.x, fmaf(a.y, b.y, fmaf(a.z, b.z, a.w * b.w)));
}

// ---------------------------------------------------------------- init slots
__global__ __launch_bounds__(256) void k_init_slots(
    const float* __restrict__ slots_in, float* __restrict__ slots,
    float* __restrict__ positions, float* __restrict__ scales) {
    int tid = blockIdx.x * 256 + threadIdx.x;
    if (tid < BB * SS * DD) {
        int s = (tid / DD) % SS;
        int c = tid % DD;
        slots[tid] = slots_in[s * 68 + c];
    }
    if (tid < BB * SS * 2) {
        int s = (tid >> 1) & 7;
        int p = tid & 1;
        float po = slots_in[s * 68 + 64 + p];
        positions[tid] = fminf(fmaxf(po, -1.f), 1.f);
        float sc = slots_in[s * 68 + 66 + p];
        scales[tid] = fminf(fmaxf(sc, 1e-3f), 2.f);
    }
}

// ---------------------------------------------------------------- prep W1-derived constants
__global__ __launch_bounds__(256) void k_prep_w(
    const float* __restrict__ W1, const float* __restrict__ lpg,
    const float* __restrict__ lpb, const float* __restrict__ b1,
    const float* __restrict__ Wg,
    float* __restrict__ W1p, float* __restrict__ avec, float* __restrict__ bvec,
    float* __restrict__ s1vec, float* __restrict__ b1p, float* __restrict__ wgc) {
    __shared__ float w1s[128 * 68];
    int tid = threadIdx.x;
    for (int q = 0; q < 8; q++) {
        int flat = q * 1024 + tid * 4;
        int o = flat >> 6, c = flat & 63;
        *(float4*)(w1s + o * 68 + c) = *(const float4*)(W1 + flat);
    }
    __syncthreads();
    if (tid < 128) {
        int o = tid;
        float a = 0.f, bv = 0.f, s1 = 0.f, b1a = b1[o];
        for (int c = 0; c < 64; c++) {
            float w0 = w1s[o * 68 + c];
            float w = w0 * lpg[c];
            W1p[o * 64 + c] = w;
            a = fmaf(w, Wg[2 * c], a);
            bv = fmaf(w, Wg[2 * c + 1], bv);
            s1 += w;
            b1a = fmaf(w0, lpb[c], b1a);
        }
        avec[o] = a; bvec[o] = bv; s1vec[o] = s1; b1p[o] = b1a;
    }
    if (tid == 128) {
        float mwA = 0.f, mwB = 0.f, AA = 0.f, BBv = 0.f, AB = 0.f;
        for (int c = 0; c < 64; c++) {
            float wa = Wg[2 * c], wb = Wg[2 * c + 1];
            mwA += wa; mwB += wb;
            AA = fmaf(wa, wa, AA); BBv = fmaf(wb, wb, BBv); AB = fmaf(wa, wb, AB);
        }
        wgc[0] = mwA * (1.f / 64.f);
        wgc[1] = mwB * (1.f / 64.f);
        wgc[2] = AA * (1.f / 64.f);
        wgc[3] = BBv * (1.f / 64.f);
        wgc[4] = AB * (2.f / 64.f);
    }
}

// ---------------------------------------------------------------- composite weights
// Wall[0][o][c] = sum_d W1p[o][d] Wk[d][c]; Wall[1] with Wv; cu[o] = W1p[o]·bg
__global__ __launch_bounds__(256) void k_prep_w2(
    const float* __restrict__ W1p, const float* __restrict__ Wk,
    const float* __restrict__ Wv, const float* __restrict__ bg,
    float* __restrict__ Wall, float* __restrict__ cu) {
    int flat = blockIdx.x * 256 + threadIdx.x;   // 64 blocks -> 16384
    int mat = flat >> 13, rem = flat & 8191;
    int o = rem >> 6, c = rem & 63;
    const float* Wm = mat ? Wv : Wk;
    float acc = 0.f;
    for (int d = 0; d < 64; d++)
        acc = fmaf(W1p[o * 64 + d], Wm[d * 64 + c], acc);
    Wall[flat] = acc;
    if (flat < 128) {
        float a = 0.f;
        for (int d = 0; d < 64; d++) a = fmaf(W1p[flat * 64 + d], bg[d], a);
        cu[flat] = a;
    }
}

// ---------------------------------------------------------------- main prep GEMM
// grid (1024, 3): chunk 0 -> uk, 1 -> uv, 2 -> moments (k,v not stored)
__global__ __launch_bounds__(256) void k_prep_main(
    const float* __restrict__ inp, const float* __restrict__ Wall,
    const float* __restrict__ cu, const float* __restrict__ Wk,
    const float* __restrict__ Wv, const float* __restrict__ bg,
    const float* __restrict__ Wg,
    float* __restrict__ uk, float* __restrict__ uv,
    float* __restrict__ kaux, float* __restrict__ vaux, float* __restrict__ gbuf) {
    __shared__ float A[64 * 68];        // 17408 B
    __shared__ float Bw[128 * 68];      // 34816 B (reused as 64x132 transpose buf)
    __shared__ float wg2[132];
    __shared__ float bgs[64];
    __shared__ float cus[128];
    int tid = threadIdx.x;
    int chunk = blockIdx.y;
    int rowBase = blockIdx.x * 64;
    {   // stage feats (cols 0..63)
        int r = tid >> 2, cq = (tid & 3) * 16;
        const float* src = inp + (size_t)(rowBase + r) * CIN + cq;
        float* dst = A + r * 68 + cq;
        #pragma unroll
        for (int q = 0; q < 8; q++) {
            float2 tv = *(const float2*)(src + 2 * q);
            dst[2 * q] = tv.x; dst[2 * q + 1] = tv.y;
        }
    }
    if (chunk < 2) {
        const float* Wsrc = Wall + (size_t)chunk * 8192;
        int o = tid >> 1, c0 = (tid & 1) * 32;
        #pragma unroll
        for (int q = 0; q < 8; q++)
            *(float4*)(Bw + o * 68 + c0 + 4 * q) = *(const float4*)(Wsrc + o * 64 + c0 + 4 * q);
        if (tid < 128) cus[tid] = cu[tid];
    } else {
        int o = tid >> 1, c0 = (tid & 1) * 32;
        const float* Wsrc = (o < 64) ? (Wk + o * 64) : (Wv + (o - 64) * 64);
        #pragma unroll
        for (int q = 0; q < 8; q++)
            *(float4*)(Bw + o * 68 + c0 + 4 * q) = *(const float4*)(Wsrc + c0 + 4 * q);
        if (tid < 64) {
            wg2[tid] = Wg[2 * tid]; wg2[66 + tid] = Wg[2 * tid + 1];
            bgs[tid] = bg[tid];
        }
    }
    __syncthreads();
    int r2 = tid >> 3, j = tid & 7;
    float acc0[16], acc1[16];
    #pragma unroll
    for (int q = 0; q < 16; q++) { acc0[q] = 0.f; acc1[q] = 0.f; }
    for (int c4 = 0; c4 < 64; c4 += 4) {
        float4 a0 = *(const float4*)(A + r2 * 68 + c4);
        float4 a1 = *(const float4*)(A + (r2 + 32) * 68 + c4);
        #pragma unroll
        for (int q = 0; q < 16; q++) {
            float4 w = *(const float4*)(Bw + (8 * q + j) * 68 + c4);
            acc0[q] += dot4(a0, w);
            acc1[q] += dot4(a1, w);
        }
    }
    if (chunk < 2) {
        float cub[16];
        #pragma unroll
        for (int q = 0; q < 16; q++) cub[q] = cus[8 * q + j];
        __syncthreads();
        #pragma unroll
        for (int q = 0; q < 16; q++) {
            Bw[r2 * 132 + 8 * q + j] = acc0[q] + cub[q];
            Bw[(r2 + 32) * 132 + 8 * q + j] = acc1[q] + cub[q];
        }
        __syncthreads();
        float* dst = (chunk == 0) ? uk : uv;
        int r = tid >> 2, c0 = (tid & 3) * 32;
        #pragma unroll
        for (int q = 0; q < 8; q++)
            *(float4*)(dst + (size_t)(rowBase + r) * 128 + c0 + 4 * q) =
                *(const float4*)(Bw + r * 132 + c0 + 4 * q);
    } else {
        float mk[2] = {0.f, 0.f}, kk[2] = {0.f, 0.f}, kA[2] = {0.f, 0.f}, kB[2] = {0.f, 0.f};
        float mv[2] = {0.f, 0.f}, vv[2] = {0.f, 0.f}, vA[2] = {0.f, 0.f}, vB[2] = {0.f, 0.f};
        #pragma unroll
        for (int q = 0; q < 8; q++) {
            int ch = 8 * q + j;
            float bgv = bgs[ch], wa = wg2[ch], wb = wg2[66 + ch];
            float x0 = acc0[q] + bgv, x1 = acc1[q] + bgv;
            mk[0] += x0; kk[0] = fmaf(x0, x0, kk[0]); kA[0] = fmaf(x0, wa, kA[0]); kB[0] = fmaf(x0, wb, kB[0]);
            mk[1] += x1; kk[1] = fmaf(x1, x1, kk[1]); kA[1] = fmaf(x1, wa, kA[1]); kB[1] = fmaf(x1, wb, kB[1]);
            float y0 = acc0[q + 8] + bgv, y1 = acc1[q + 8] + bgv;
            mv[0] += y0; vv[0] = fmaf(y0, y0, vv[0]); vA[0] = fmaf(y0, wa, vA[0]); vB[0] = fmaf(y0, wb, vB[0]);
            mv[1] += y1; vv[1] = fmaf(y1, y1, vv[1]); vA[1] = fmaf(y1, wa, vA[1]); vB[1] = fmaf(y1, wb, vB[1]);
        }
        #pragma unroll
        for (int off = 1; off <= 4; off <<= 1) {
            #pragma unroll
            for (int rr = 0; rr < 2; rr++) {
                mk[rr] += __shfl_xor(mk[rr], off, 64); kk[rr] += __shfl_xor(kk[rr], off, 64);
                kA[rr] += __shfl_xor(kA[rr], off, 64); kB[rr] += __shfl_xor(kB[rr], off, 64);
                mv[rr] += __shfl_xor(mv[rr], off, 64); vv[rr] += __shfl_xor(vv[rr], off, 64);
                vA[rr] += __shfl_xor(vA[rr], off, 64); vB[rr] += __shfl_xor(vB[rr], off, 64);
            }
        }
        if (j == 0) {
            #pragma unroll
            for (int rr = 0; rr < 2; rr++) {
                int row = rowBase + r2 + rr * 32;
                float g0 = inp[(size_t)row * CIN + 64];
                float g1 = inp[(size_t)row * CIN + 65];
                float4 m1 = {mk[rr] * (1.f / 64.f), kk[rr] * (1.f / 64.f),
                             kA[rr] * (1.f / 32.f), kB[rr] * (1.f / 32.f)};
                float4 m2 = {g0, g1, 0.f, 0.f};
                *(float4*)(kaux + (size_t)row * 8) = m1;
                *(float4*)(kaux + (size_t)row * 8 + 4) = m2;
                float4 n1 = {mv[rr] * (1.f / 64.f), vv[rr] * (1.f / 64.f),
                             vA[rr] * (1.f / 32.f), vB[rr] * (1.f / 32.f)};
                *(float4*)(vaux + (size_t)row * 8) = n1;
                *(float4*)(vaux + (size_t)row * 8 + 4) = m2;
                *(float2*)(gbuf + (size_t)row * 2) = {g0, g1};
            }
        }
    }
}

// ---------------------------------------------------------------- slot_prep: w2q, qb2
__global__ __launch_bounds__(512) void k_slot_prep(
    const float* __restrict__ slots, const float* __restrict__ lsg,
    const float* __restrict__ lsb, const float* __restrict__ Wq,
    const float* __restrict__ W2, const float* __restrict__ b2,
    float* __restrict__ w2q, float* __restrict__ qb2) {
    __shared__ float sn[512];
    __shared__ float qv[SS][64];
    __shared__ float wsum[8], wsum2[8];
    int b = blockIdx.x, t = threadIdx.x;
    int s = t >> 6, c = t & 63;
    float x = slots[(b * SS + s) * DD + c];
    float sum = x;
    for (int off = 32; off; off >>= 1) sum += __shfl_xor(sum, off, 64);
    float m = sum * (1.f / 64.f);
    float dv = x - m;
    float vs = dv * dv;
    for (int off = 32; off; off >>= 1) vs += __shfl_xor(vs, off, 64);
    float y = dv * rsqrtf(vs * (1.f / 64.f) + LN_EPS_F) * lsg[c] + lsb[c];
    float s1 = y, s2 = y * y;
    for (int off = 32; off; off >>= 1) { s1 += __shfl_xor(s1, off, 64); s2 += __shfl_xor(s2, off, 64); }
    if (c == 0) { wsum[s] = s1; wsum2[s] = s2; }
    __syncthreads();
    float ts1 = 0.f, ts2 = 0.f;
    #pragma unroll
    for (int i = 0; i < 8; i++) { ts1 += wsum[i]; ts2 += wsum2[i]; }
    float gm = ts1 * (1.f / 512.f);
    float gv = ts2 * (1.f / 512.f) - gm * gm;
    sn[t] = (y - gm) * rsqrtf(gv + LN_EPS_F);
    __syncthreads();
    float acc = 0.f;
    for (int j4 = 0; j4 < 64; j4 += 4)
        acc += dot4(*(const float4*)&sn[s * 64 + j4], *(const float4*)(Wq + c * 64 + j4));
    qv[s][c] = acc;
    __syncthreads();
    float a0 = 0.f, a1 = 0.f;
    for (int cc = 0; cc < 64; cc++) {
        float qc = qv[s][cc];
        a0 = fmaf(qc, W2[cc * DHH + c], a0);
        a1 = fmaf(qc, W2[cc * DHH + c + 64], a1);
    }
    w2q[(b * SS + s) * DHH + c] = a0 * QSCALE;
    w2q[(b * SS + s) * DHH + c + 64] = a1 * QSCALE;
    float qb = qv[s][c] * b2[c];
    for (int off = 32; off; off >>= 1) qb += __shfl_xor(qb, off, 64);
    if (c == 0) qb2[b * SS + s] = qb * QSCALE;
}

// ---------------------------------------------------------------- pass1: dots
__global__ __launch_bounds__(256) void k_pass1(
    const float* __restrict__ uk, const float* __restrict__ kaux,
    const float* __restrict__ positions, const float* __restrict__ scales,
    const float* __restrict__ avec, const float* __restrict__ bvec,
    const float* __restrict__ s1vec, const float* __restrict__ b1p,
    const float* __restrict__ wgc, const float* __restrict__ w2q,
    const float* __restrict__ qb2, float* __restrict__ dots) {
    int tid = threadIdx.x;
    int chunk = blockIdx.x, b = blockIdx.y;
    int wv = tid >> 6, lane = tid & 63, rh = lane >> 5, ol = lane & 31;
    int o4 = ol * 4;
    float4 a4 = *(const float4*)(avec + o4);
    float4 bv4 = *(const float4*)(bvec + o4);
    float4 s14 = *(const float4*)(s1vec + o4);
    float4 b14 = *(const float4*)(b1p + o4);
    float mwA = wgc[0], mwB = wgc[1], AA = wgc[2], BBc = wgc[3], AB2 = wgc[4];
    float p0[8], p1[8], rc0[8], rc1[8], qb[8];
    float4 wq[8];
    #pragma unroll
    for (int s = 0; s < 8; s++) {
        int bs = b * 8 + s;
        p0[s] = positions[bs * 2]; p1[s] = positions[bs * 2 + 1];
        rc0[s] = 1.f / scales[bs * 2]; rc1[s] = 1.f / scales[bs * 2 + 1];
        qb[s] = qb2[bs];
        wq[s] = *(const float4*)(w2q + (size_t)bs * DHH + o4);
    }
    int row0 = chunk * 64 + wv * 16 + rh;
    size_t rg = (size_t)b * NN + row0;
    float4 m1 = *(const float4*)(kaux + rg * 8);
    float4 m2 = *(const float4*)(kaux + rg * 8 + 4);
    float4 u4 = *(const float4*)(uk + rg * 128 + o4);
    for (int st = 0; st < 8; st++) {
        float4 n1, n2, nu;
        if (st < 7) {
            size_t rgn = rg + (size_t)(st + 1) * 2;
            n1 = *(const float4*)(kaux + rgn * 8);
            n2 = *(const float4*)(kaux + rgn * 8 + 4);
            nu = *(const float4*)(uk + rgn * 128 + o4);
        }
        int row = row0 + st * 2;
        #pragma unroll
        for (int s = 0; s < 8; s++) {
            float rel0 = (m2.x - p0[s]) * rc0[s];
            float rel1 = (m2.y - p1[s]) * rc1[s];
            float m = fmaf(rel1, mwB, fmaf(rel0, mwA, m1.x));
            float q2 = fmaf(rel0, fmaf(rel0, AA, m1.z), m1.y);
            q2 = fmaf(rel1, fmaf(rel1, BBc, m1.w), q2);
            q2 = fmaf(rel0 * rel1, AB2, q2);
            float var = fmaf(-m, m, q2);
            float rstd = rsqrtf(fmaxf(var, 0.f) + LN_EPS_F);
            float p = 0.f, t, h;
            t = fmaf(-m, s14.x, u4.x); t = fmaf(rel0, a4.x, t); t = fmaf(rel1, bv4.x, t);
            h = fmaf(rstd, t, b14.x); p = fmaf(fmaxf(h, 0.f), wq[s].x, p);
            t = fmaf(-m, s14.y, u4.y); t = fmaf(rel0, a4.y, t); t = fmaf(rel1, bv4.y, t);
            h = fmaf(rstd, t, b14.y); p = fmaf(fmaxf(h, 0.f), wq[s].y, p);
            t = fmaf(-m, s14.z, u4.z); t = fmaf(rel0, a4.z, t); t = fmaf(rel1, bv4.z, t);
            h = fmaf(rstd, t, b14.z); p = fmaf(fmaxf(h, 0.f), wq[s].z, p);
            t = fmaf(-m, s14.w, u4.w); t = fmaf(rel0, a4.w, t); t = fmaf(rel1, bv4.w, t);
            h = fmaf(rstd, t, b14.w); p = fmaf(fmaxf(h, 0.f), wq[s].w, p);
            p += __shfl_xor(p, 1, 64);
            p += __shfl_xor(p, 2, 64);
            p += __shfl_xor(p, 4, 64);
            p += __shfl_xor(p, 8, 64);
            p += __shfl_xor(p, 16, 64);
            if (ol == 0)
                dots[(size_t)(b * 8 + s) * NN + row] = p + qb[s];
        }
        m1 = n1; m2 = n2; u4 = nu;
    }
}

// ---------------------------------------------------------------- pass2: H
__global__ __launch_bounds__(256) void k_pass2(
    const float* __restrict__ uv, const float* __restrict__ vaux,
    const float* __restrict__ positions, const float* __restrict__ scales,
    const float* __restrict__ avec, const float* __restrict__ bvec,
    const float* __restrict__ s1vec, const float* __restrict__ b1p,
    const float* __restrict__ wgc, const float* __restrict__ attn,
    float* __restrict__ H) {
    __shared__ float Hw[4 * 1024];
    int tid = threadIdx.x;
    int chunk = blockIdx.x, b = blockIdx.y;
    int wv = tid >> 6, lane = tid & 63, rh = lane >> 5, ol = lane & 31;
    int o4 = ol * 4;
    float4 a4 = *(const float4*)(avec + o4);
    float4 bv4 = *(const float4*)(bvec + o4);
    float4 s14 = *(const float4*)(s1vec + o4);
    float4 b14 = *(const float4*)(b1p + o4);
    float mwA = wgc[0], mwB = wgc[1], AA = wgc[2], BBc = wgc[3], AB2 = wgc[4];
    float p0[8], p1[8], rc0[8], rc1[8];
    #pragma unroll
    for (int s = 0; s < 8; s++) {
        int bs = b * 8 + s;
        p0[s] = positions[bs * 2]; p1[s] = positions[bs * 2 + 1];
        rc0[s] = 1.f / scales[bs * 2]; rc1[s] = 1.f / scales[bs * 2 + 1];
    }
    float hq[8][4];
    #pragma unroll
    for (int s = 0; s < 8; s++)
        #pragma unroll
        for (int c = 0; c < 4; c++) hq[s][c] = 0.f;
    int row0 = chunk * 64 + wv * 16 + rh;
    size_t rg = (size_t)b * NN + row0;
    float4 m1 = *(const float4*)(vaux + rg * 8);
    float4 m2 = *(const float4*)(vaux + rg * 8 + 4);
    float4 u4 = *(const float4*)(uv + rg * 128 + o4);
    for (int st = 0; st < 8; st++) {
        float4 n1, n2, nu;
        if (st < 7) {
            size_t rgn = rg + (size_t)(st + 1) * 2;
            n1 = *(const float4*)(vaux + rgn * 8);
            n2 = *(const float4*)(vaux + rgn * 8 + 4);
            nu = *(const float4*)(uv + rgn * 128 + o4);
        }
        int row = row0 + st * 2;
        #pragma unroll
        for (int s = 0; s < 8; s++) {
            float ar = attn[(size_t)(b * 8 + s) * NN + row];
            float rel0 = (m2.x - p0[s]) * rc0[s];
            float rel1 = (m2.y - p1[s]) * rc1[s];
            float m = fmaf(rel1, mwB, fmaf(rel0, mwA, m1.x));
            float q2 = fmaf(rel0, fmaf(rel0, AA, m1.z), m1.y);
            q2 = fmaf(rel1, fmaf(rel1, BBc, m1.w), q2);
            q2 = fmaf(rel0 * rel1, AB2, q2);
            float var = fmaf(-m, m, q2);
            float rstd = rsqrtf(fmaxf(var, 0.f) + LN_EPS_F);
            float t, h;
            t = fmaf(-m, s14.x, u4.x); t = fmaf(rel0, a4.x, t); t = fmaf(rel1, bv4.x, t);
            h = fmaf(rstd, t, b14.x); hq[s][0] = fmaf(ar, fmaxf(h, 0.f), hq[s][0]);
            t = fmaf(-m, s14.y, u4.y); t = fmaf(rel0, a4.y, t); t = fmaf(rel1, bv4.y, t);
            h = fmaf(rstd, t, b14.y); hq[s][1] = fmaf(ar, fmaxf(h, 0.f), hq[s][1]);
            t = fmaf(-m, s14.z, u4.z); t = fmaf(rel0, a4.z, t); t = fmaf(rel1, bv4.z, t);
            h = fmaf(rstd, t, b14.z); hq[s][2] = fmaf(ar, fmaxf(h, 0.f), hq[s][2]);
            t = fmaf(-m, s14.w, u4.w); t = fmaf(rel0, a4.w, t); t = fmaf(rel1, bv4.w, t);
            h = fmaf(rstd, t, b14.w); hq[s][3] = fmaf(ar, fmaxf(h, 0.f), hq[s][3]);
        }
        m1 = n1; m2 = n2; u4 = nu;
    }
    #pragma unroll
    for (int s = 0; s < 8; s++)
        #pragma unroll
        for (int c = 0; c < 4; c++)
            hq[s][c] += __shfl_xor(hq[s][c], 32, 64);
    if (lane < 32) {
        #pragma unroll
        for (int s = 0; s < 8; s++) {
            float4 st = {hq[s][0], hq[s][1], hq[s][2], hq[s][3]};
            *(float4*)(Hw + wv * 1024 + s * 128 + o4) = st;
        }
    }
    __syncthreads();
    #pragma unroll
    for (int q = 0; q < 4; q++) {
        int flat = q * 256 + tid;
        float sum = Hw[flat] + Hw[1024 + flat] + Hw[2048 + flat] + Hw[3072 + flat];
        atomicAdd(&H[(size_t)b * 8 * DHH + flat], sum);
    }
}

// ---------------------------------------------------------------- softmax M,L (+H zero)
__global__ __launch_bounds__(256) void k_softmax_ms(
    const float* __restrict__ dots, float* __restrict__ Mv, float* __restrict__ Lv,
    float* __restrict__ H) {
    __shared__ float red[4];
    int bs = blockIdx.x, t = threadIdx.x;
    if (t < 128) H[(size_t)bs * DHH + t] = 0.f;
    const float* dp = dots + (size_t)bs * NN;
    float mx = -1e30f;
    #pragma unroll
    for (int it = 0; it < 4; it++) {
        float4 d = *(const float4*)(dp + it * 1024 + t * 4);
        mx = fmaxf(mx, fmaxf(fmaxf(d.x, d.y), fmaxf(d.z, d.w)));
    }
    for (int off = 32; off; off >>= 1) mx = fmaxf(mx, __shfl_xor(mx, off, 64));
    if ((t & 63) == 0) red[t >> 6] = mx;
    __syncthreads();
    float M = fmaxf(fmaxf(red[0], red[1]), fmaxf(red[2], red[3]));
    __syncthreads();
    float sm = 0.f;
    #pragma unroll
    for (int it = 0; it < 4; it++) {
        float4 d = *(const float4*)(dp + it * 1024 + t * 4);
        sm += expf(d.x - M) + expf(d.y - M) + expf(d.z - M) + expf(d.w - M);
    }
    for (int off = 32; off; off >>= 1) sm += __shfl_xor(sm, off, 64);
    if ((t & 63) == 0) red[t >> 6] = sm;
    __syncthreads();
    if (t == 0) { Mv[bs] = M; Lv[bs] = red[0] + red[1] + red[2] + red[3]; }
}

// ---------------------------------------------------------------- attn normalize
__global__ __launch_bounds__(256) void k_attn(
    const float* __restrict__ dots, const float* __restrict__ Mv,
    const float* __restrict__ Lv, float* __restrict__ attn) {
    int chunk = blockIdx.x, b = blockIdx.y;
    int n = chunk * 256 + threadIdx.x;
    float a[8];
    float rs = 0.f;
    #pragma unroll
    for (int s = 0; s < 8; s++) {
        int bs = b * 8 + s;
        float d = dots[(size_t)bs * NN + n];
        a[s] = expf(d - Mv[bs]) * (1.f / Lv[bs]) + EPS_ATTN_F;
        rs += a[s];
    }
    float inv = 1.f / rs;
    #pragma unroll
    for (int s = 0; s < 8; s++)
        attn[(size_t)(b * 8 + s) * NN + n] = a[s] * inv;
}

// ---------------------------------------------------------------- stats + finalize
__global__ __launch_bounds__(256) void k_stats(
    const float* __restrict__ attn, const float* __restrict__ gbuf,
    float* __restrict__ positions, float* __restrict__ scales,
    float* __restrict__ stats) {
    __shared__ float red[4][5];
    int bs = blockIdx.x, b = bs >> 3, t = threadIdx.x;
    const float* ap = attn + (size_t)bs * NN;
    const float* gb = gbuf + (size_t)b * NN * 2;
    float v0 = 0.f, v1 = 0.f, v2 = 0.f, v3 = 0.f, v4 = 0.f;
    #pragma unroll
    for (int it = 0; it < 4; it++) {
        int n0 = it * 1024 + t * 4;
        float4 av = *(const float4*)(ap + n0);
        float4 g1 = *(const float4*)(gb + (size_t)n0 * 2);
        float4 g2 = *(const float4*)(gb + (size_t)n0 * 2 + 4);
        v0 += av.x + av.y + av.z + av.w;
        v1 = fmaf(av.x, g1.x, fmaf(av.y, g1.z, fmaf(av.z, g2.x, fmaf(av.w, g2.z, v1))));
        v2 = fmaf(av.x, g1.y, fmaf(av.y, g1.w, fmaf(av.z, g2.y, fmaf(av.w, g2.w, v2))));
        v3 = fmaf(av.x, g1.x * g1.x, fmaf(av.y, g1.z * g1.z, fmaf(av.z, g2.x * g2.x, fmaf(av.w, g2.z * g2.z, v3))));
        v4 = fmaf(av.x, g1.y * g1.y, fmaf(av.y, g1.w * g1.w, fmaf(av.z, g2.y * g2.y, fmaf(av.w, g2.w * g2.w, v4))));
    }
    for (int off = 32; off; off >>= 1) {
        v0 += __shfl_xor(v0, off, 64); v1 += __shfl_xor(v1, off, 64);
        v2 += __shfl_xor(v2, off, 64); v3 += __shfl_xor(v3, off, 64);
        v4 += __shfl_xor(v4, off, 64);
    }
    if ((t & 63) == 0) {
        int w = t >> 6;
        red[w][0] = v0; red[w][1] = v1; red[w][2] = v2; red[w][3] = v3; red[w][4] = v4;
    }
    __syncthreads();
    if (t == 0) {
        float A0 = red[0][0] + red[1][0] + red[2][0] + red[3][0];
        float A1x = red[0][1] + red[1][1] + red[2][1] + red[3][1];
        float A1y = red[0][2] + red[1][2] + red[2][2] + red[3][2];
        float A2x = red[0][3] + red[1][3] + red[2][3] + red[3][3];
        float A2y = red[0][4] + red[1][4] + red[2][4] + red[3][4];
        positions[bs * 2 + 0] = A1x;
        positions[bs * 2 + 1] = A1y;
        float sx = A2x - A1x * A1x * (2.f - A0);
        float sy = A2y - A1y * A1y * (2.f - A0);
        scales[bs * 2 + 0] = fminf(fmaxf(sqrtf(fmaxf(sx, 0.f)), 1e-3f), 2.f);
        scales[bs * 2 + 1] = fminf(fmaxf(sqrtf(fmaxf(sy, 0.f)), 1e-3f), 2.f);
        stats[bs] = A0;
    }
}

// ---------------------------------------------------------------- GRU + slot MLP
__global__ __launch_bounds__(64) void k_gru_mlp(
    const float* __restrict__ H, const float* __restrict__ stats,
    const float* __restrict__ W2, const float* __restrict__ b2,
    const float* __restrict__ W_ih, const float* __restrict__ W_hh,
    const float* __restrict__ b_ih, const float* __restrict__ b_hh,
    const float* __restrict__ lmg, const float* __restrict__ lmb,
    const float* __restrict__ W3, const float* __restrict__ b3,
    const float* __restrict__ W4, const float* __restrict__ b4,
    float* __restrict__ slots) {
    int bs = blockIdx.x;
    int c = threadIdx.x;
    __shared__ float hl[DHH], ul[DD], sl[DD], yl[DD], hml[DHH];
    hl[c] = H[bs * DHH + c];
    hl[c + 64] = H[bs * DHH + 64 + c];
    float hold = slots[bs * DD + c];
    sl[c] = hold;
    __syncthreads();
    float A0 = stats[bs];
    float u = A0 * b2[c];
    for (int o = 0; o < DHH; o += 4) {
        float4 w = *(const float4*)(W2 + c * DHH + o);
        u = fmaf(w.x, hl[o], fmaf(w.y, hl[o + 1], fmaf(w.z, hl[o + 2], fmaf(w.w, hl[o + 3], u))));
    }
    ul[c] = u;
    __syncthreads();
    float gir = b_ih[c], giz = b_ih[64 + c], gin = b_ih[128 + c];
    float ghr = b_hh[c], ghz = b_hh[64 + c], ghn = b_hh[128 + c];
    for (int k4 = 0; k4 < DD; k4 += 4) {
        float4 uu = *(const float4*)(ul + k4);
        float4 hh = *(const float4*)(sl + k4);
        gir += dot4(uu, *(const float4*)(W_ih + c * DD + k4));
        giz += dot4(uu, *(const float4*)(W_ih + (64 + c) * DD + k4));
        gin += dot4(uu, *(const float4*)(W_ih + (128 + c) * DD + k4));
        ghr += dot4(hh, *(const float4*)(W_hh + c * DD + k4));
        ghz += dot4(hh, *(const float4*)(W_hh + (64 + c) * DD + k4));
        ghn += dot4(hh, *(const float4*)(W_hh + (128 + c) * DD + k4));
    }
    float rg = 1.f / (1.f + expf(-(gir + ghr)));
    float zg = 1.f / (1.f + expf(-(giz + ghz)));
    float ng = tanhf(gin + rg * ghn);
    float snew = (1.f - zg) * ng + zg * hold;
    float sum = snew;
    for (int off = 32; off; off >>= 1) sum += __shfl_xor(sum, off, 64);
    float m = sum * (1.f / 64.f);
    float dv = snew - m;
    float vv = dv * dv;
    for (int off = 32; off; off >>= 1) vv += __shfl_xor(vv, off, 64);
    yl[c] = dv * rsqrtf(vv * (1.f / 64.f) + LN_EPS_F) * lmg[c] + lmb[c];
    __syncthreads();
    float h0 = b3[c], h1 = b3[64 + c];
    for (int k4 = 0; k4 < DD; k4 += 4) {
        float4 yy = *(const float4*)(yl + k4);
        h0 += dot4(yy, *(const float4*)(W3 + c * DD + k4));
        h1 += dot4(yy, *(const float4*)(W3 + (64 + c) * DD + k4));
    }
    hml[c] = fmaxf(h0, 0.f);
    hml[64 + c] = fmaxf(h1, 0.f);
    __syncthreads();
    float outv = b4[c];
    for (int o4 = 0; o4 < DHH; o4 += 4) {
        float4 hm4 = *(const float4*)(hml + o4);
        outv += dot4(hm4, *(const float4*)(W4 + c * DHH + o4));
    }
    slots[bs * DD + c] = outv;
}

// ---------------------------------------------------------------- write out
__global__ __launch_bounds__(256) void k_write_out(
    const float* __restrict__ slots, const float* __restrict__ positions,
    const float* __restrict__ scales, float* __restrict__ out) {
    int tid = blockIdx.x * 256 + threadIdx.x;
    if (tid >= BB * SS * 68) return;
    int bs = tid / 68, c = tid % 68;
    float v;
    if (c < 64) v = slots[bs * 64 + c];
    else if (c < 66) v = positions[bs * 2 + (c - 64)];
    else v = scales[bs * 2 + (c - 66)];
    out[tid] = v;
}

// ---------------------------------------------------------------- launcher
extern "C" void kernel_launch(void* const* d_in, const int* in_sizes, int n_in,
                              void* d_out, int out_size, void* d_ws, size_t ws_size,
                              hipStream_t stream) {
    (void)in_sizes; (void)n_in; (void)out_size; (void)ws_size;
    const float* inp = (const float*)d_in[0];
    const float* slots_in = (const float*)d_in[1];
    const float* Wq = (const float*)d_in[2];
    const float* Wk = (const float*)d_in[3];
    const float* Wv = (const float*)d_in[4];
    const float* Wg = (const float*)d_in[5];
    const float* bg = (const float*)d_in[6];
    const float* lpg = (const float*)d_in[7];
    const float* lpb = (const float*)d_in[8];
    const float* W1 = (const float*)d_in[9];
    const float* b1 = (const float*)d_in[10];
    const float* W2 = (const float*)d_in[11];
    const float* b2 = (const float*)d_in[12];
    const float* W_ih = (const float*)d_in[13];
    const float* W_hh = (const float*)d_in[14];
    const float* b_ih = (const float*)d_in[15];
    const float* b_hh = (const float*)d_in[16];
    const float* lmg = (const float*)d_in[17];
    const float* lmb = (const float*)d_in[18];
    const float* W3 = (const float*)d_in[19];
    const float* b3 = (const float*)d_in[20];
    const float* W4 = (const float*)d_in[21];
    const float* b4 = (const float*)d_in[22];
    const float* lsg = (const float*)d_in[23];
    const float* lsb = (const float*)d_in[24];
    float* out = (float*)d_out;
    float* ws = (float*)d_ws;

    const size_t NR = (size_t)BB * NN;
    size_t o_uk = 0;
    size_t o_uv = o_uk + NR * 128;
    size_t o_kaux = o_uv + NR * 128;
    size_t o_vaux = o_kaux + NR * 8;
    size_t o_gbuf = o_vaux + NR * 8;
    size_t o_dots = o_gbuf + NR * 2;
    size_t o_attn = o_dots + NR * SS;
    size_t o_slots = o_attn + NR * SS;
    size_t o_pos = o_slots + BB * SS * DD;
    size_t o_scl = o_pos + BB * SS * 2;
    size_t o_w2q = o_scl + BB * SS * 2;
    size_t o_qb2 = o_w2q + BB * SS * DHH;
    size_t o_Mv = o_qb2 + BB * SS;
    size_t o_Lv = o_Mv + BB * SS;
    size_t o_H = o_Lv + BB * SS;
    size_t o_stats = o_H + BB * SS * DHH;
    size_t o_W1p = o_stats + BB * SS;
    size_t o_avec = o_W1p + DHH * DD;
    size_t o_bvec = o_avec + DHH;
    size_t o_s1v = o_bvec + DHH;
    size_t o_b1p = o_s1v + DHH;
    size_t o_wgc = o_b1p + DHH;
    size_t o_Wall = o_wgc + 8;
    size_t o_cu = o_Wall + 2 * DHH * DD;

    float* uk = ws + o_uk;
    float* uv = ws + o_uv;
    float* kaux = ws + o_kaux;
    float* vaux = ws + o_vaux;
    float* gbuf = ws + o_gbuf;
    float* dots = ws + o_dots;
    float* attn = ws + o_attn;
    float* slots = ws + o_slots;
    float* positions = ws + o_pos;
    float* scales = ws + o_scl;
    float* w2q = ws + o_w2q;
    float* qb2 = ws + o_qb2;
    float* Mv = ws + o_Mv;
    float* Lv = ws + o_Lv;
    float* H = ws + o_H;
    float* stats = ws + o_stats;
    float* W1p = ws + o_W1p;
    float* avec = ws + o_avec;
    float* bvec = ws + o_bvec;
    float* s1v = ws + o_s1v;
    float* b1p = ws + o_b1p;
    float* wgc = ws + o_wgc;
    float* Wall = ws + o_Wall;
    float* cu = ws + o_cu;

    k_init_slots<<<32, 256, 0, stream>>>(slots_in, slots, positions, scales);
    k_prep_w<<<1, 256, 0, stream>>>(W1, lpg, lpb, b1, Wg, W1p, avec, bvec, s1v, b1p, wgc);
    k_prep_w2<<<64, 256, 0, stream>>>(W1p, Wk, Wv, bg, Wall, cu);
    k_prep_main<<<dim3(1024, 3), 256, 0, stream>>>(inp, Wall, cu, Wk, Wv, bg, Wg,
                                                   uk, uv, kaux, vaux, gbuf);

    for (int it = 0; it <= NITERS; ++it) {
        k_slot_prep<<<BB, 512, 0, stream>>>(slots, lsg, lsb, Wq, W2, b2, w2q, qb2);
        k_pass1<<<dim3(64, BB), 256, 0, stream>>>(uk, kaux, positions, scales,
                                                  avec, bvec, s1v, b1p, wgc, w2q, qb2, dots);
        k_softmax_ms<<<BB * SS, 256, 0, stream>>>(dots, Mv, Lv, H);
        k_attn<<<dim3(16, BB), 256, 0, stream>>>(dots, Mv, Lv, attn);
        if (it < NITERS) {
            k_pass2<<<dim3(64, BB), 256, 0, stream>>>(uv, vaux, positions, scales,
                                                      avec, bvec, s1v, b1p, wgc, attn, H);
            k_stats<<<BB * SS, 256, 0, stream>>>(attn, gbuf, positions, scales, stats);
            k_gru_mlp<<<BB * SS, 64, 0, stream>>>(H, stats, W2, b2, W_ih, W_hh, b_ih, b_hh,
                                                  lmg, lmb, W3, b3, W4, b4, slots);
        } else {
            k_stats<<<BB * SS, 256, 0, stream>>>(attn, gbuf, positions, scales, stats);
        }
    }
    k_write_out<<<34, 256, 0, stream>>>(slots, positions, scales, out);
}